// Round 1
// baseline (394.277 us; speedup 1.0000x reference)
//
#include <hip/hip_runtime.h>
#include <hip/hip_bf16.h>

// Problem: B=2048, DIM=2048, SKETCH=256, SIZE=131072
//   sx = normalize_rows(x @ R); out = 1 - max_row(sx @ buffer^T)

#define BROWS 2048
#define DIM   2048
#define SKDIM 256
#define NBUF  131072

typedef __attribute__((ext_vector_type(4))) float f32x4;
typedef __attribute__((ext_vector_type(8))) short bf16x8;
typedef __attribute__((ext_vector_type(4))) short bf16x4;

static __device__ inline unsigned short f2bf(float f) {
  unsigned u = __float_as_uint(f);
  unsigned r = u + 0x7FFFu + ((u >> 16) & 1u);  // round-to-nearest-even
  return (unsigned short)(r >> 16);
}

static __device__ inline bf16x8 cvt8(const float* __restrict__ p) {
  f32x4 a = *(const f32x4*)p;
  f32x4 b = *(const f32x4*)(p + 4);
  bf16x8 r;
  r[0] = (short)f2bf(a[0]); r[1] = (short)f2bf(a[1]);
  r[2] = (short)f2bf(a[2]); r[3] = (short)f2bf(a[3]);
  r[4] = (short)f2bf(b[0]); r[5] = (short)f2bf(b[1]);
  r[6] = (short)f2bf(b[2]); r[7] = (short)f2bf(b[3]);
  return r;
}

// K0: RT_bf[n][k] = bf16(R[k][n])   (256 x 2048)
__global__ void transpose_R(const float* __restrict__ R, unsigned short* __restrict__ rt) {
  int idx = blockIdx.x * 256 + threadIdx.x;   // over DIM*SKDIM = 524288
  int k = idx >> 8, n = idx & 255;
  rt[n * DIM + k] = f2bf(R[idx]);
}

// K1: buffer f32 -> bf16 (131072 x 256)
__global__ void conv_buf(const float* __restrict__ in, unsigned short* __restrict__ outb) {
  const int nvec = (NBUF * SKDIM) / 4;  // 8388608 float4s
  int stride = gridDim.x * blockDim.x;
  for (int i = blockIdx.x * blockDim.x + threadIdx.x; i < nvec; i += stride) {
    f32x4 v = ((const f32x4*)in)[i];
    bf16x4 r;
    r[0] = (short)f2bf(v[0]); r[1] = (short)f2bf(v[1]);
    r[2] = (short)f2bf(v[2]); r[3] = (short)f2bf(v[3]);
    ((bf16x4*)outb)[i] = r;
  }
}

// K2: sx_bf = normalize_rows(x @ RT^T). Block: 64 rows x 256 cols, K-loop 2048.
// 4 waves, wave w owns cols [w*64, w*64+64).
__launch_bounds__(256)
__global__ void gemm_sketch(const float* __restrict__ x, const unsigned short* __restrict__ rt,
                            unsigned short* __restrict__ sx) {
  __shared__ unsigned short As[64][72];    // 64 x 64 bf16, stride 72 (pad)
  __shared__ unsigned short Bs[256][72];   // 256 x 64 bf16
  __shared__ float ssum[4][64];

  const int m0 = blockIdx.x * 64;
  const int tid = threadIdx.x;
  const int w = tid >> 6, l = tid & 63;
  const int lr = l & 15, q = l >> 4;

  f32x4 acc[4][4] = {};

  for (int k0 = 0; k0 < DIM; k0 += 64) {
    // stage A (f32 -> bf16): 64 rows x 8 vec8 = 512 vec8s, 2 per thread
    #pragma unroll
    for (int i = 0; i < 2; ++i) {
      int v = tid + i * 256;
      int r = v >> 3, vc = v & 7;
      *(bf16x8*)&As[r][vc * 8] = cvt8(x + (size_t)(m0 + r) * DIM + k0 + vc * 8);
    }
    // stage B (bf16 copy): 256 rows x 8 vec8 = 2048 vec8s, 8 per thread
    #pragma unroll
    for (int i = 0; i < 8; ++i) {
      int v = tid + i * 256;
      int r = v >> 3, vc = v & 7;
      *(bf16x8*)&Bs[r][vc * 8] = *(const bf16x8*)(rt + (size_t)r * DIM + k0 + vc * 8);
    }
    __syncthreads();
    #pragma unroll
    for (int ks = 0; ks < 2; ++ks) {
      int kk = ks * 32 + q * 8;
      bf16x8 a[4], b[4];
      #pragma unroll
      for (int mi = 0; mi < 4; ++mi) a[mi] = *(bf16x8*)&As[mi * 16 + lr][kk];
      #pragma unroll
      for (int ni = 0; ni < 4; ++ni) b[ni] = *(bf16x8*)&Bs[w * 64 + ni * 16 + lr][kk];
      #pragma unroll
      for (int mi = 0; mi < 4; ++mi)
        #pragma unroll
        for (int ni = 0; ni < 4; ++ni)
          acc[mi][ni] = __builtin_amdgcn_mfma_f32_16x16x32_bf16(a[mi], b[ni], acc[mi][ni], 0, 0, 0);
    }
    __syncthreads();
  }

  // row sums of squares (this wave's 64 cols), reduce across the 16-lane group
  float ps[4][4];
  #pragma unroll
  for (int mi = 0; mi < 4; ++mi)
    #pragma unroll
    for (int rg = 0; rg < 4; ++rg) {
      float s = acc[mi][0][rg] * acc[mi][0][rg] + acc[mi][1][rg] * acc[mi][1][rg]
              + acc[mi][2][rg] * acc[mi][2][rg] + acc[mi][3][rg] * acc[mi][3][rg];
      #pragma unroll
      for (int m = 1; m < 16; m <<= 1) s += __shfl_xor(s, m);
      ps[mi][rg] = s;
    }
  if (lr == 0) {
    #pragma unroll
    for (int mi = 0; mi < 4; ++mi)
      #pragma unroll
      for (int rg = 0; rg < 4; ++rg)
        ssum[w][mi * 16 + q * 4 + rg] = ps[mi][rg];
  }
  __syncthreads();

  // scale + store bf16
  #pragma unroll
  for (int mi = 0; mi < 4; ++mi)
    #pragma unroll
    for (int rg = 0; rg < 4; ++rg) {
      int r = mi * 16 + q * 4 + rg;
      float tot = ssum[0][r] + ssum[1][r] + ssum[2][r] + ssum[3][r];
      float inv = 1.0f / fmaxf(sqrtf(tot), 1e-12f);
      #pragma unroll
      for (int ni = 0; ni < 4; ++ni) {
        float val = acc[mi][ni][rg] * inv;
        sx[(size_t)(m0 + r) * SKDIM + w * 64 + ni * 16 + lr] = f2bf(val);
      }
    }
}

// K3: sim = sx_bf @ buf_bf^T with fused row-max. Block tile 128x128, K=256.
// 4 waves in 2x2; wave (wr,wc) owns 64x64 at (wr*64, wc*64).
__launch_bounds__(256)
__global__ void gemm_sim(const unsigned short* __restrict__ sx,
                         const unsigned short* __restrict__ bufb,
                         float* __restrict__ partial) {
  __shared__ unsigned short As[128][72];
  __shared__ unsigned short Bs[128][72];
  __shared__ float rmax[2][128];

  const int bn = blockIdx.x;           // 0..1023 col tile
  const int m0 = blockIdx.y * 128;     // 0..15 row tile
  const size_t n0 = (size_t)bn * 128;
  const int tid = threadIdx.x;
  const int w = tid >> 6, l = tid & 63;
  const int wr = w >> 1, wc = w & 1;
  const int lr = l & 15, q = l >> 4;

  f32x4 acc[4][4] = {};

  for (int k0 = 0; k0 < SKDIM; k0 += 64) {
    #pragma unroll
    for (int i = 0; i < 4; ++i) {
      int v = tid + i * 256;
      int r = v >> 3, vc = v & 7;
      *(bf16x8*)&As[r][vc * 8] = *(const bf16x8*)(sx + (size_t)(m0 + r) * SKDIM + k0 + vc * 8);
    }
    #pragma unroll
    for (int i = 0; i < 4; ++i) {
      int v = tid + i * 256;
      int r = v >> 3, vc = v & 7;
      *(bf16x8*)&Bs[r][vc * 8] = *(const bf16x8*)(bufb + (n0 + r) * SKDIM + k0 + vc * 8);
    }
    __syncthreads();
    #pragma unroll
    for (int ks = 0; ks < 2; ++ks) {
      int kk = ks * 32 + q * 8;
      bf16x8 a[4], b[4];
      #pragma unroll
      for (int mi = 0; mi < 4; ++mi) a[mi] = *(bf16x8*)&As[wr * 64 + mi * 16 + lr][kk];
      #pragma unroll
      for (int ni = 0; ni < 4; ++ni) b[ni] = *(bf16x8*)&Bs[wc * 64 + ni * 16 + lr][kk];
      #pragma unroll
      for (int mi = 0; mi < 4; ++mi)
        #pragma unroll
        for (int ni = 0; ni < 4; ++ni)
          acc[mi][ni] = __builtin_amdgcn_mfma_f32_16x16x32_bf16(a[mi], b[ni], acc[mi][ni], 0, 0, 0);
    }
    __syncthreads();
  }

  // per-row max over this wave's 64 cols
  float pm[4][4];
  #pragma unroll
  for (int mi = 0; mi < 4; ++mi)
    #pragma unroll
    for (int rg = 0; rg < 4; ++rg) {
      float v = fmaxf(fmaxf(acc[mi][0][rg], acc[mi][1][rg]),
                      fmaxf(acc[mi][2][rg], acc[mi][3][rg]));
      #pragma unroll
      for (int m = 1; m < 16; m <<= 1) v = fmaxf(v, __shfl_xor(v, m));
      pm[mi][rg] = v;
    }
  if (lr == 0) {
    #pragma unroll
    for (int mi = 0; mi < 4; ++mi)
      #pragma unroll
      for (int rg = 0; rg < 4; ++rg)
        rmax[wc][wr * 64 + mi * 16 + q * 4 + rg] = pm[mi][rg];
  }
  __syncthreads();

  if (tid < 128) {
    float v = fmaxf(rmax[0][tid], rmax[1][tid]);
    partial[(size_t)(m0 + tid) * 1024 + bn] = v;
  }
}

// K4: out[r] = 1 - max_c partial[r][c]
__global__ void reduce_max(const float* __restrict__ partial, float* __restrict__ out) {
  const int r = blockIdx.x;
  const int tid = threadIdx.x;
  float m = -3.0e38f;
  for (int c = tid; c < 1024; c += 256) m = fmaxf(m, partial[(size_t)r * 1024 + c]);
  #pragma unroll
  for (int s = 1; s < 64; s <<= 1) m = fmaxf(m, __shfl_xor(m, s));
  __shared__ float wm[4];
  if ((tid & 63) == 0) wm[tid >> 6] = m;
  __syncthreads();
  if (tid == 0) {
    float mm = fmaxf(fmaxf(wm[0], wm[1]), fmaxf(wm[2], wm[3]));
    out[r] = 1.0f - mm;
  }
}

extern "C" void kernel_launch(void* const* d_in, const int* in_sizes, int n_in,
                              void* d_out, int out_size, void* d_ws, size_t ws_size,
                              hipStream_t stream) {
  const float* x   = (const float*)d_in[0];   // [2048, 2048]
  const float* R   = (const float*)d_in[1];   // [2048, 256]
  const float* buf = (const float*)d_in[2];   // [131072, 256]
  float* out = (float*)d_out;                  // [2048]

  char* ws = (char*)d_ws;
  // ws layout (bytes): rt 1MB | buf_bf 64MB | sx_bf 1MB | partial 8MB  (~74MB)
  unsigned short* rt     = (unsigned short*)(ws);
  unsigned short* bufb   = (unsigned short*)(ws + (1ull << 20));
  unsigned short* sxb    = (unsigned short*)(ws + (1ull << 20) + (64ull << 20));
  float*          part   = (float*)         (ws + (1ull << 20) + (64ull << 20) + (1ull << 20));

  transpose_R<<<dim3((DIM * SKDIM) / 256), dim3(256), 0, stream>>>(R, rt);
  conv_buf<<<dim3(2048), dim3(256), 0, stream>>>(buf, bufb);
  gemm_sketch<<<dim3(BROWS / 64), dim3(256), 0, stream>>>(x, rt, sxb);
  gemm_sim<<<dim3(NBUF / 128, BROWS / 128), dim3(256), 0, stream>>>(sxb, bufb, part);
  reduce_max<<<dim3(BROWS), dim3(256), 0, stream>>>(part, out);
}

// Round 2
// 253.909 us; speedup vs baseline: 1.5528x; 1.5528x over previous
//
#include <hip/hip_runtime.h>
#include <hip/hip_bf16.h>

// Problem: B=2048, DIM=2048, SKETCH=256, SIZE=131072
//   sx = normalize_rows(x @ R); out = 1 - max_row(sx @ buffer^T)

#define BROWS 2048
#define DIM   2048
#define SKDIM 256
#define NBUF  131072
#define NT    8                    // n-tiles (128 cols each) per block
#define NGROUPS (NBUF / (128 * NT))  // 128

typedef __attribute__((ext_vector_type(4))) float f32x4;
typedef __attribute__((ext_vector_type(8))) short bf16x8;
typedef __attribute__((ext_vector_type(4))) short bf16x4;

static __device__ inline unsigned short f2bf(float f) {
  unsigned u = __float_as_uint(f);
  unsigned r = u + 0x7FFFu + ((u >> 16) & 1u);  // round-to-nearest-even
  return (unsigned short)(r >> 16);
}

static __device__ inline bf16x8 cvt8(const float* __restrict__ p) {
  f32x4 a = *(const f32x4*)p;
  f32x4 b = *(const f32x4*)(p + 4);
  bf16x8 r;
  r[0] = (short)f2bf(a[0]); r[1] = (short)f2bf(a[1]);
  r[2] = (short)f2bf(a[2]); r[3] = (short)f2bf(a[3]);
  r[4] = (short)f2bf(b[0]); r[5] = (short)f2bf(b[1]);
  r[6] = (short)f2bf(b[2]); r[7] = (short)f2bf(b[3]);
  return r;
}

// K0: RT_bf[n][k] = bf16(R[k][n])   (256 x 2048)
__global__ void transpose_R(const float* __restrict__ R, unsigned short* __restrict__ rt) {
  int idx = blockIdx.x * 256 + threadIdx.x;
  int k = idx >> 8, n = idx & 255;
  rt[n * DIM + k] = f2bf(R[idx]);
}

// K1: buffer f32 -> bf16 (131072 x 256)
__global__ void conv_buf(const float* __restrict__ in, unsigned short* __restrict__ outb) {
  const int nvec = (NBUF * SKDIM) / 4;
  int stride = gridDim.x * blockDim.x;
  for (int i = blockIdx.x * blockDim.x + threadIdx.x; i < nvec; i += stride) {
    f32x4 v = ((const f32x4*)in)[i];
    bf16x4 r;
    r[0] = (short)f2bf(v[0]); r[1] = (short)f2bf(v[1]);
    r[2] = (short)f2bf(v[2]); r[3] = (short)f2bf(v[3]);
    ((bf16x4*)outb)[i] = r;
  }
}

// K2: sx_bf = normalize_rows(x @ RT^T). Block: 64 rows x 256 cols. (unchanged, passed R0)
__launch_bounds__(256)
__global__ void gemm_sketch(const float* __restrict__ x, const unsigned short* __restrict__ rt,
                            unsigned short* __restrict__ sx) {
  __shared__ unsigned short As[64][72];
  __shared__ unsigned short Bs[256][72];
  __shared__ float ssum[4][64];

  const int m0 = blockIdx.x * 64;
  const int tid = threadIdx.x;
  const int w = tid >> 6, l = tid & 63;
  const int lr = l & 15, q = l >> 4;

  f32x4 acc[4][4] = {};

  for (int k0 = 0; k0 < DIM; k0 += 64) {
    #pragma unroll
    for (int i = 0; i < 2; ++i) {
      int v = tid + i * 256;
      int r = v >> 3, vc = v & 7;
      *(bf16x8*)&As[r][vc * 8] = cvt8(x + (size_t)(m0 + r) * DIM + k0 + vc * 8);
    }
    #pragma unroll
    for (int i = 0; i < 8; ++i) {
      int v = tid + i * 256;
      int r = v >> 3, vc = v & 7;
      *(bf16x8*)&Bs[r][vc * 8] = *(const bf16x8*)(rt + (size_t)r * DIM + k0 + vc * 8);
    }
    __syncthreads();
    #pragma unroll
    for (int ks = 0; ks < 2; ++ks) {
      int kk = ks * 32 + q * 8;
      bf16x8 a[4], b[4];
      #pragma unroll
      for (int mi = 0; mi < 4; ++mi) a[mi] = *(bf16x8*)&As[mi * 16 + lr][kk];
      #pragma unroll
      for (int ni = 0; ni < 4; ++ni) b[ni] = *(bf16x8*)&Bs[w * 64 + ni * 16 + lr][kk];
      #pragma unroll
      for (int mi = 0; mi < 4; ++mi)
        #pragma unroll
        for (int ni = 0; ni < 4; ++ni)
          acc[mi][ni] = __builtin_amdgcn_mfma_f32_16x16x32_bf16(a[mi], b[ni], acc[mi][ni], 0, 0, 0);
    }
    __syncthreads();
  }

  float ps[4][4];
  #pragma unroll
  for (int mi = 0; mi < 4; ++mi)
    #pragma unroll
    for (int rg = 0; rg < 4; ++rg) {
      float s = acc[mi][0][rg] * acc[mi][0][rg] + acc[mi][1][rg] * acc[mi][1][rg]
              + acc[mi][2][rg] * acc[mi][2][rg] + acc[mi][3][rg] * acc[mi][3][rg];
      #pragma unroll
      for (int m = 1; m < 16; m <<= 1) s += __shfl_xor(s, m);
      ps[mi][rg] = s;
    }
  if (lr == 0) {
    #pragma unroll
    for (int mi = 0; mi < 4; ++mi)
      #pragma unroll
      for (int rg = 0; rg < 4; ++rg)
        ssum[w][mi * 16 + q * 4 + rg] = ps[mi][rg];
  }
  __syncthreads();

  #pragma unroll
  for (int mi = 0; mi < 4; ++mi)
    #pragma unroll
    for (int rg = 0; rg < 4; ++rg) {
      int r = mi * 16 + q * 4 + rg;
      float tot = ssum[0][r] + ssum[1][r] + ssum[2][r] + ssum[3][r];
      float inv = 1.0f / fmaxf(sqrtf(tot), 1e-12f);
      #pragma unroll
      for (int ni = 0; ni < 4; ++ni) {
        float val = acc[mi][ni][rg] * inv;
        sx[(size_t)(m0 + r) * SKDIM + w * 64 + ni * 16 + lr] = f2bf(val);
      }
    }
}

// K3 v2: sim row-max, m97-structure + n-tile persistence.
// Block: 128 rows x (NT x 128) cols. 4 waves (2x2), wave tile 64x64, acc 4x4.
// LDS: linear As[128][64], Bs[128][64] bf16 (16KB each), staged via
// global_load_lds width 16; 2-barrier K-step loop (stage; sync; compute; sync).
// Per n-tile: fold acc into running per-lane row-max, reset acc. C never stored.
__launch_bounds__(256, 3)
__global__ void gemm_sim(const unsigned short* __restrict__ sx,
                         const unsigned short* __restrict__ bufb,
                         float* __restrict__ partial) {
  __shared__ unsigned short As[128 * 64];
  __shared__ unsigned short Bs[128 * 64];
  __shared__ float rmaxs[2][128];

  // XCD-aware bijective swizzle (nwg = 2048, divisible by 8), then m-fastest
  // decode so 16 consecutive logical blocks share one B panel (L2 reuse,
  // XCD-exclusive B columns).
  const int gid = blockIdx.x;
  const int swz = (gid & 7) * (NGROUPS * 16 / 8) + (gid >> 3);
  const int bm = swz & 15;         // m-tile 0..15
  const int ng = swz >> 4;         // n-group 0..127
  const int m0 = bm * 128;

  const int tid = threadIdx.x;
  const int w = tid >> 6, l = tid & 63;
  const int wr = w >> 1, wc = w & 1;
  const int lr = l & 15, q = l >> 4;
  const int lrow8 = l >> 3;            // staging: row-in-chunk 0..7
  const int lcol = (l & 7) * 8;        // staging: col 0..56

  f32x4 acc[4][4] = {};
  float rm[4][4];
  #pragma unroll
  for (int mi = 0; mi < 4; ++mi)
    #pragma unroll
    for (int rg = 0; rg < 4; ++rg) rm[mi][rg] = -3.0e38f;

  for (int it = 0; it < NT * 4; ++it) {
    const int nt = it >> 2, ks = it & 3;
    const int k0 = ks * 64;
    const int nb0 = ng * (NT * 128) + nt * 128;

    // stage A[128][64] and B[128][64] via global_load_lds (16B/lane).
    // chunk c = w*4+i covers rows [c*8, c*8+8) = 1KB of LDS; lane l writes
    // bytes [c*1024 + l*16). Global src is per-lane; LDS dst linear.
    #pragma unroll
    for (int i = 0; i < 4; ++i) {
      const int c = w * 4 + i;
      const int row = c * 8 + lrow8;
      const unsigned short* gp = sx + (size_t)(m0 + row) * SKDIM + k0 + lcol;
      __builtin_amdgcn_global_load_lds(
          (const __attribute__((address_space(1))) unsigned int*)gp,
          (__attribute__((address_space(3))) unsigned int*)(&As[c * 512 + l * 8]),
          16, 0, 0);
    }
    #pragma unroll
    for (int i = 0; i < 4; ++i) {
      const int c = w * 4 + i;
      const int row = c * 8 + lrow8;
      const unsigned short* gp = bufb + (size_t)(nb0 + row) * SKDIM + k0 + lcol;
      __builtin_amdgcn_global_load_lds(
          (const __attribute__((address_space(1))) unsigned int*)gp,
          (__attribute__((address_space(3))) unsigned int*)(&Bs[c * 512 + l * 8]),
          16, 0, 0);
    }
    asm volatile("s_waitcnt vmcnt(0)" ::: "memory");
    __syncthreads();

    #pragma unroll
    for (int ks2 = 0; ks2 < 2; ++ks2) {
      const int kk = ks2 * 32 + q * 8;
      bf16x8 a[4], b[4];
      #pragma unroll
      for (int mi = 0; mi < 4; ++mi) a[mi] = *(const bf16x8*)&As[(wr * 64 + mi * 16 + lr) * 64 + kk];
      #pragma unroll
      for (int ni = 0; ni < 4; ++ni) b[ni] = *(const bf16x8*)&Bs[(wc * 64 + ni * 16 + lr) * 64 + kk];
      #pragma unroll
      for (int mi = 0; mi < 4; ++mi)
        #pragma unroll
        for (int ni = 0; ni < 4; ++ni)
          acc[mi][ni] = __builtin_amdgcn_mfma_f32_16x16x32_bf16(a[mi], b[ni], acc[mi][ni], 0, 0, 0);
    }
    __syncthreads();

    if (ks == 3) {  // n-tile done: fold into running row-max, reset acc
      #pragma unroll
      for (int mi = 0; mi < 4; ++mi)
        #pragma unroll
        for (int rg = 0; rg < 4; ++rg) {
          float v = fmaxf(fmaxf(acc[mi][0][rg], acc[mi][1][rg]),
                          fmaxf(acc[mi][2][rg], acc[mi][3][rg]));
          rm[mi][rg] = fmaxf(rm[mi][rg], v);
          #pragma unroll
          for (int ni = 0; ni < 4; ++ni) acc[mi][ni][rg] = 0.0f;
        }
    }
  }

  // cross-lane (col) reduce over the 16-lane group, then cross-wave-col via LDS
  #pragma unroll
  for (int mi = 0; mi < 4; ++mi)
    #pragma unroll
    for (int rg = 0; rg < 4; ++rg) {
      float v = rm[mi][rg];
      v = fmaxf(v, __shfl_xor(v, 1));
      v = fmaxf(v, __shfl_xor(v, 2));
      v = fmaxf(v, __shfl_xor(v, 4));
      v = fmaxf(v, __shfl_xor(v, 8));
      if (lr == 0) rmaxs[wc][wr * 64 + mi * 16 + q * 4 + rg] = v;
    }
  __syncthreads();
  if (tid < 128) {
    float v = fmaxf(rmaxs[0][tid], rmaxs[1][tid]);
    partial[(size_t)(m0 + tid) * NGROUPS + ng] = v;
  }
}

// K4: out[r] = 1 - max_c partial[r][c], 128 cols, one wave per row
__global__ void reduce_max(const float* __restrict__ partial, float* __restrict__ out) {
  const int r = blockIdx.x;
  const int l = threadIdx.x;  // 64
  float m = fmaxf(partial[(size_t)r * NGROUPS + l], partial[(size_t)r * NGROUPS + 64 + l]);
  #pragma unroll
  for (int s = 1; s < 64; s <<= 1) m = fmaxf(m, __shfl_xor(m, s));
  if (l == 0) out[r] = 1.0f - m;
}

extern "C" void kernel_launch(void* const* d_in, const int* in_sizes, int n_in,
                              void* d_out, int out_size, void* d_ws, size_t ws_size,
                              hipStream_t stream) {
  const float* x   = (const float*)d_in[0];   // [2048, 2048]
  const float* R   = (const float*)d_in[1];   // [2048, 256]
  const float* buf = (const float*)d_in[2];   // [131072, 256]
  float* out = (float*)d_out;                  // [2048]

  char* ws = (char*)d_ws;
  // ws layout: rt 1MB | buf_bf 64MB | sx_bf 1MB | partial 1MB
  unsigned short* rt   = (unsigned short*)(ws);
  unsigned short* bufb = (unsigned short*)(ws + (1ull << 20));
  unsigned short* sxb  = (unsigned short*)(ws + (1ull << 20) + (64ull << 20));
  float*          part = (float*)         (ws + (1ull << 20) + (64ull << 20) + (1ull << 20));

  transpose_R<<<dim3((DIM * SKDIM) / 256), dim3(256), 0, stream>>>(R, rt);
  conv_buf<<<dim3(2048), dim3(256), 0, stream>>>(buf, bufb);
  gemm_sketch<<<dim3(BROWS / 64), dim3(256), 0, stream>>>(x, rt, sxb);
  gemm_sim<<<dim3(16 * NGROUPS), dim3(256), 0, stream>>>(sxb, bufb, part);
  reduce_max<<<dim3(BROWS), dim3(64), 0, stream>>>(part, out);
}

// Round 3
// 234.673 us; speedup vs baseline: 1.6801x; 1.0820x over previous
//
#include <hip/hip_runtime.h>
#include <hip/hip_bf16.h>

// Problem: B=2048, DIM=2048, SKETCH=256, SIZE=131072
//   sx = normalize_rows(x @ R); out = 1 - max_row(sx @ buffer^T)

#define BROWS 2048
#define DIM   2048
#define SKDIM 256
#define NBUF  131072

// gemm_sim v3 geometry: 256 blocks, each 256 rows x 4096 cols, BK=32,
// quad-buffered LDS pipeline (stage t+3 while computing t), counted vmcnt.
#define NGROUPS 32            // n-chunks (4096 cols each)
#define NT_PER  16            // 256-col n-tiles per block
#define NITER   (NT_PER * 8)  // 8 K-steps (BK=32) per n-tile = 128

typedef __attribute__((ext_vector_type(4))) float f32x4;
typedef __attribute__((ext_vector_type(8))) short bf16x8;
typedef __attribute__((ext_vector_type(4))) short bf16x4;

static __device__ inline unsigned short f2bf(float f) {
  unsigned u = __float_as_uint(f);
  unsigned r = u + 0x7FFFu + ((u >> 16) & 1u);  // round-to-nearest-even
  return (unsigned short)(r >> 16);
}

static __device__ inline bf16x8 cvt8(const float* __restrict__ p) {
  f32x4 a = *(const f32x4*)p;
  f32x4 b = *(const f32x4*)(p + 4);
  bf16x8 r;
  r[0] = (short)f2bf(a[0]); r[1] = (short)f2bf(a[1]);
  r[2] = (short)f2bf(a[2]); r[3] = (short)f2bf(a[3]);
  r[4] = (short)f2bf(b[0]); r[5] = (short)f2bf(b[1]);
  r[6] = (short)f2bf(b[2]); r[7] = (short)f2bf(b[3]);
  return r;
}

// K0: RT_bf[n][k] = bf16(R[k][n])   (256 x 2048)
__global__ void transpose_R(const float* __restrict__ R, unsigned short* __restrict__ rt) {
  int idx = blockIdx.x * 256 + threadIdx.x;
  int k = idx >> 8, n = idx & 255;
  rt[n * DIM + k] = f2bf(R[idx]);
}

// K1: buffer f32 -> bf16 (131072 x 256)
__global__ void conv_buf(const float* __restrict__ in, unsigned short* __restrict__ outb) {
  const int nvec = (NBUF * SKDIM) / 4;
  int stride = gridDim.x * blockDim.x;
  for (int i = blockIdx.x * blockDim.x + threadIdx.x; i < nvec; i += stride) {
    f32x4 v = ((const f32x4*)in)[i];
    bf16x4 r;
    r[0] = (short)f2bf(v[0]); r[1] = (short)f2bf(v[1]);
    r[2] = (short)f2bf(v[2]); r[3] = (short)f2bf(v[3]);
    ((bf16x4*)outb)[i] = r;
  }
}

// K2: sx_bf = normalize_rows(x @ RT^T). (unchanged; validated R0/R1)
__launch_bounds__(256)
__global__ void gemm_sketch(const float* __restrict__ x, const unsigned short* __restrict__ rt,
                            unsigned short* __restrict__ sx) {
  __shared__ unsigned short As[64][72];
  __shared__ unsigned short Bs[256][72];
  __shared__ float ssum[4][64];

  const int m0 = blockIdx.x * 64;
  const int tid = threadIdx.x;
  const int w = tid >> 6, l = tid & 63;
  const int lr = l & 15, q = l >> 4;

  f32x4 acc[4][4] = {};

  for (int k0 = 0; k0 < DIM; k0 += 64) {
    #pragma unroll
    for (int i = 0; i < 2; ++i) {
      int v = tid + i * 256;
      int r = v >> 3, vc = v & 7;
      *(bf16x8*)&As[r][vc * 8] = cvt8(x + (size_t)(m0 + r) * DIM + k0 + vc * 8);
    }
    #pragma unroll
    for (int i = 0; i < 8; ++i) {
      int v = tid + i * 256;
      int r = v >> 3, vc = v & 7;
      *(bf16x8*)&Bs[r][vc * 8] = *(const bf16x8*)(rt + (size_t)r * DIM + k0 + vc * 8);
    }
    __syncthreads();
    #pragma unroll
    for (int ks = 0; ks < 2; ++ks) {
      int kk = ks * 32 + q * 8;
      bf16x8 a[4], b[4];
      #pragma unroll
      for (int mi = 0; mi < 4; ++mi) a[mi] = *(bf16x8*)&As[mi * 16 + lr][kk];
      #pragma unroll
      for (int ni = 0; ni < 4; ++ni) b[ni] = *(bf16x8*)&Bs[w * 64 + ni * 16 + lr][kk];
      #pragma unroll
      for (int mi = 0; mi < 4; ++mi)
        #pragma unroll
        for (int ni = 0; ni < 4; ++ni)
          acc[mi][ni] = __builtin_amdgcn_mfma_f32_16x16x32_bf16(a[mi], b[ni], acc[mi][ni], 0, 0, 0);
    }
    __syncthreads();
  }

  float ps[4][4];
  #pragma unroll
  for (int mi = 0; mi < 4; ++mi)
    #pragma unroll
    for (int rg = 0; rg < 4; ++rg) {
      float s = acc[mi][0][rg] * acc[mi][0][rg] + acc[mi][1][rg] * acc[mi][1][rg]
              + acc[mi][2][rg] * acc[mi][2][rg] + acc[mi][3][rg] * acc[mi][3][rg];
      #pragma unroll
      for (int m = 1; m < 16; m <<= 1) s += __shfl_xor(s, m);
      ps[mi][rg] = s;
    }
  if (lr == 0) {
    #pragma unroll
    for (int mi = 0; mi < 4; ++mi)
      #pragma unroll
      for (int rg = 0; rg < 4; ++rg)
        ssum[w][mi * 16 + q * 4 + rg] = ps[mi][rg];
  }
  __syncthreads();

  #pragma unroll
  for (int mi = 0; mi < 4; ++mi)
    #pragma unroll
    for (int rg = 0; rg < 4; ++rg) {
      int r = mi * 16 + q * 4 + rg;
      float tot = ssum[0][r] + ssum[1][r] + ssum[2][r] + ssum[3][r];
      float inv = 1.0f / fmaxf(sqrtf(tot), 1e-12f);
      #pragma unroll
      for (int ni = 0; ni < 4; ++ni) {
        float val = acc[mi][ni][rg] * inv;
        sx[(size_t)(m0 + r) * SKDIM + w * 64 + ni * 16 + lr] = f2bf(val);
      }
    }
}

// K3 v3: sim row-max. 512 threads, 8 waves (2 wr x 4 wc), wave tile 128x64.
// LDS: 4 slots x (A[256][32] + B[256][32]) bf16 = 4 x 32KB = 128KB.
// Pipeline: iter t stages tile t+3 (4 global_load_lds/thread), waits
// vmcnt(12) (counted, never 0 in steady state), raw s_barrier, swizzled
// ds_read frags, lgkmcnt(0)+barrier, setprio(1) + 32 MFMA + setprio(0).
// T2 swizzle: 16B-slot ^= (row&3), applied to global SOURCE on stage (LDS dest
// linear, required by global_load_lds) and to ds_read address (rule #21).
__launch_bounds__(512, 2)
__global__ void gemm_sim(const unsigned short* __restrict__ sx,
                         const unsigned short* __restrict__ bufb,
                         float* __restrict__ partial) {
  __shared__ __align__(16) char lb[131072];

  // XCD-chunked swizzle (256 blocks, 8 XCDs -> 32 logical ids each), m-fastest
  // inner so the 8 co-resident m-blocks of one n-chunk co-read B via L2.
  const int gid = blockIdx.x;
  const int logical = (gid & 7) * 32 + (gid >> 3);
  const int mt = logical & 7;        // 0..7 m-tile (256 rows)
  const int nc = logical >> 3;       // 0..31 n-chunk (4096 cols)
  const int m0 = mt * 256;
  const int ncbase = nc * (NT_PER * 256);

  const int tid = threadIdx.x;
  const int w = tid >> 6, l = tid & 63;
  const int wr = w >> 2, wc = w & 3;        // wave grid 2 x 4
  const int lr = l & 15, q = l >> 4;

  // staging lane constants: thread covers (row = j*128 + tid>>2, 16B slot tid&3)
  const int srow = tid >> 2;                       // 0..127
  const int scol = ((tid & 3) ^ (srow & 3)) * 8;   // pre-swizzled source col (elems)
  // read-side swizzle (row&3 == lr&3 since frag-row bases are mult of 4)
  const int axor = (q ^ (lr & 3)) << 4;

  f32x4 acc[8][4] = {};
  float rm[8][4];
  #pragma unroll
  for (int mi = 0; mi < 8; ++mi)
    #pragma unroll
    for (int rg = 0; rg < 4; ++rg) rm[mi][rg] = -3.0e38f;

#define STAGE(u) do {                                                          \
    const int s_ = (u) & 3;                                                    \
    const int k0_ = ((u) & 7) * 32;                                            \
    const int n0_ = ncbase + ((u) >> 3) * 256;                                 \
    char* dA_ = lb + s_ * 32768;                                               \
    char* dB_ = dA_ + 16384;                                                   \
    _Pragma("unroll")                                                          \
    for (int j_ = 0; j_ < 2; ++j_) {                                           \
      const int row_ = j_ * 128 + srow;                                        \
      const unsigned short* ga_ = sx + (size_t)(m0 + row_) * SKDIM + k0_ + scol; \
      __builtin_amdgcn_global_load_lds(                                        \
          (const __attribute__((address_space(1))) unsigned int*)ga_,          \
          (__attribute__((address_space(3))) unsigned int*)(dA_ + j_ * 8192 + tid * 16), \
          16, 0, 0);                                                           \
      const unsigned short* gb_ = bufb + (size_t)(n0_ + row_) * SKDIM + k0_ + scol; \
      __builtin_amdgcn_global_load_lds(                                        \
          (const __attribute__((address_space(1))) unsigned int*)gb_,          \
          (__attribute__((address_space(3))) unsigned int*)(dB_ + j_ * 8192 + tid * 16), \
          16, 0, 0);                                                           \
    }                                                                          \
  } while (0)

  // prologue: 3 tiles in flight
  STAGE(0); STAGE(1); STAGE(2);

  for (int t = 0; t < NITER; ++t) {
    const int rem = (NITER - 1) - t;
    if (rem >= 3) {
      STAGE(t + 3);
      asm volatile("s_waitcnt vmcnt(12)" ::: "memory");
    } else if (rem == 2) {
      asm volatile("s_waitcnt vmcnt(8)" ::: "memory");
    } else if (rem == 1) {
      asm volatile("s_waitcnt vmcnt(4)" ::: "memory");
    } else {
      asm volatile("s_waitcnt vmcnt(0)" ::: "memory");
    }
    asm volatile("s_barrier" ::: "memory");   // slot t fully staged (all waves)

    const int soff = (t & 3) * 32768;
    const char* pa = lb + soff + (wr * 128 + lr) * 64 + axor;
    const char* pb = lb + soff + 16384 + (wc * 64 + lr) * 64 + axor;
    bf16x8 a[8], b[4];
    #pragma unroll
    for (int mi = 0; mi < 8; ++mi) a[mi] = *(const bf16x8*)(pa + mi * 1024);
    #pragma unroll
    for (int ni = 0; ni < 4; ++ni) b[ni] = *(const bf16x8*)(pb + ni * 1024);
    asm volatile("s_waitcnt lgkmcnt(0)" ::: "memory");
    asm volatile("s_barrier" ::: "memory");   // all reads done -> slot reusable

    __builtin_amdgcn_s_setprio(1);
    #pragma unroll
    for (int mi = 0; mi < 8; ++mi)
      #pragma unroll
      for (int ni = 0; ni < 4; ++ni)
        acc[mi][ni] = __builtin_amdgcn_mfma_f32_16x16x32_bf16(a[mi], b[ni], acc[mi][ni], 0, 0, 0);
    __builtin_amdgcn_s_setprio(0);

    if ((t & 7) == 7) {  // n-tile complete: fold row-max, reset acc
      #pragma unroll
      for (int mi = 0; mi < 8; ++mi)
        #pragma unroll
        for (int rg = 0; rg < 4; ++rg) {
          float v = fmaxf(fmaxf(acc[mi][0][rg], acc[mi][1][rg]),
                          fmaxf(acc[mi][2][rg], acc[mi][3][rg]));
          rm[mi][rg] = fmaxf(rm[mi][rg], v);
          #pragma unroll
          for (int ni = 0; ni < 4; ++ni) acc[mi][ni][rg] = 0.0f;
        }
    }
  }
#undef STAGE

  // epilogue: reduce over the 16 cols held across lr lanes
  #pragma unroll
  for (int mi = 0; mi < 8; ++mi)
    #pragma unroll
    for (int rg = 0; rg < 4; ++rg) {
      float v = rm[mi][rg];
      v = fmaxf(v, __shfl_xor(v, 1));
      v = fmaxf(v, __shfl_xor(v, 2));
      v = fmaxf(v, __shfl_xor(v, 4));
      v = fmaxf(v, __shfl_xor(v, 8));
      rm[mi][rg] = v;
    }

  float* rmaxs = (float*)lb;   // reuse staging LDS: [4][256]
  if (lr == 0) {
    #pragma unroll
    for (int mi = 0; mi < 8; ++mi)
      #pragma unroll
      for (int rg = 0; rg < 4; ++rg)
        rmaxs[wc * 256 + wr * 128 + mi * 16 + q * 4 + rg] = rm[mi][rg];
  }
  __syncthreads();
  if (tid < 256) {
    float v = fmaxf(fmaxf(rmaxs[tid], rmaxs[256 + tid]),
                    fmaxf(rmaxs[512 + tid], rmaxs[768 + tid]));
    partial[(size_t)(m0 + tid) * NGROUPS + nc] = v;
  }
}

// K4: out[r] = 1 - max over 32 partials. 2 rows per 64-thread block.
__global__ void reduce_max(const float* __restrict__ partial, float* __restrict__ out) {
  const int r = blockIdx.x * 2 + (threadIdx.x >> 5);
  const int c = threadIdx.x & 31;
  float m = partial[(size_t)r * NGROUPS + c];
  #pragma unroll
  for (int s = 1; s < 32; s <<= 1) m = fmaxf(m, __shfl_xor(m, s));
  if (c == 0) out[r] = 1.0f - m;
}

extern "C" void kernel_launch(void* const* d_in, const int* in_sizes, int n_in,
                              void* d_out, int out_size, void* d_ws, size_t ws_size,
                              hipStream_t stream) {
  const float* x   = (const float*)d_in[0];   // [2048, 2048]
  const float* R   = (const float*)d_in[1];   // [2048, 256]
  const float* buf = (const float*)d_in[2];   // [131072, 256]
  float* out = (float*)d_out;                  // [2048]

  char* ws = (char*)d_ws;
  // ws layout: rt 1MB | buf_bf 64MB | sx_bf 1MB | partial 256KB
  unsigned short* rt   = (unsigned short*)(ws);
  unsigned short* bufb = (unsigned short*)(ws + (1ull << 20));
  unsigned short* sxb  = (unsigned short*)(ws + (1ull << 20) + (64ull << 20));
  float*          part = (float*)         (ws + (1ull << 20) + (64ull << 20) + (1ull << 20));

  transpose_R<<<dim3((DIM * SKDIM) / 256), dim3(256), 0, stream>>>(R, rt);
  conv_buf<<<dim3(2048), dim3(256), 0, stream>>>(buf, bufb);
  gemm_sketch<<<dim3(BROWS / 64), dim3(256), 0, stream>>>(x, rt, sxb);
  gemm_sim<<<dim3(256), dim3(512), 0, stream>>>(sxb, bufb, part);
  reduce_max<<<dim3(BROWS / 2), dim3(64), 0, stream>>>(part, out);
}

// Round 4
// 213.541 us; speedup vs baseline: 1.8464x; 1.0990x over previous
//
#include <hip/hip_runtime.h>
#include <hip/hip_bf16.h>

// Problem: B=2048, DIM=2048, SKETCH=256, SIZE=131072
//   sx = normalize_rows(x @ R); out = 1 - max_row(sx @ buffer^T)

#define BROWS 2048
#define DIM   2048
#define SKDIM 256
#define NBUF  131072

// gemm_sim v4: 256 blocks, each 256 rows x 4096 cols, BK=32,
// quad-buffered LDS, single-barrier pipelined iteration, counted vmcnt.
#define NGROUPS 32            // n-chunks (4096 cols each)
#define NT_PER  16            // 256-col n-tiles per block
#define NITER   (NT_PER * 8)  // 8 K-steps (BK=32) per n-tile = 128

typedef __attribute__((ext_vector_type(4))) float f32x4;
typedef __attribute__((ext_vector_type(8))) short bf16x8;
typedef __attribute__((ext_vector_type(4))) short bf16x4;

static __device__ inline unsigned short f2bf(float f) {
  unsigned u = __float_as_uint(f);
  unsigned r = u + 0x7FFFu + ((u >> 16) & 1u);  // round-to-nearest-even
  return (unsigned short)(r >> 16);
}

static __device__ inline bf16x8 cvt8(const float* __restrict__ p) {
  f32x4 a = *(const f32x4*)p;
  f32x4 b = *(const f32x4*)(p + 4);
  bf16x8 r;
  r[0] = (short)f2bf(a[0]); r[1] = (short)f2bf(a[1]);
  r[2] = (short)f2bf(a[2]); r[3] = (short)f2bf(a[3]);
  r[4] = (short)f2bf(b[0]); r[5] = (short)f2bf(b[1]);
  r[6] = (short)f2bf(b[2]); r[7] = (short)f2bf(b[3]);
  return r;
}

// K0: RT_bf[n][k] = bf16(R[k][n])   (256 x 2048)
__global__ void transpose_R(const float* __restrict__ R, unsigned short* __restrict__ rt) {
  int idx = blockIdx.x * 256 + threadIdx.x;
  int k = idx >> 8, n = idx & 255;
  rt[n * DIM + k] = f2bf(R[idx]);
}

// K1: buffer f32 -> bf16 (131072 x 256)
__global__ void conv_buf(const float* __restrict__ in, unsigned short* __restrict__ outb) {
  const int nvec = (NBUF * SKDIM) / 4;
  int stride = gridDim.x * blockDim.x;
  for (int i = blockIdx.x * blockDim.x + threadIdx.x; i < nvec; i += stride) {
    f32x4 v = ((const f32x4*)in)[i];
    bf16x4 r;
    r[0] = (short)f2bf(v[0]); r[1] = (short)f2bf(v[1]);
    r[2] = (short)f2bf(v[2]); r[3] = (short)f2bf(v[3]);
    ((bf16x4*)outb)[i] = r;
  }
}

// K2: sx_bf = normalize_rows(x @ RT^T). (unchanged; validated R0-R2)
__launch_bounds__(256)
__global__ void gemm_sketch(const float* __restrict__ x, const unsigned short* __restrict__ rt,
                            unsigned short* __restrict__ sx) {
  __shared__ unsigned short As[64][72];
  __shared__ unsigned short Bs[256][72];
  __shared__ float ssum[4][64];

  const int m0 = blockIdx.x * 64;
  const int tid = threadIdx.x;
  const int w = tid >> 6, l = tid & 63;
  const int lr = l & 15, q = l >> 4;

  f32x4 acc[4][4] = {};

  for (int k0 = 0; k0 < DIM; k0 += 64) {
    #pragma unroll
    for (int i = 0; i < 2; ++i) {
      int v = tid + i * 256;
      int r = v >> 3, vc = v & 7;
      *(bf16x8*)&As[r][vc * 8] = cvt8(x + (size_t)(m0 + r) * DIM + k0 + vc * 8);
    }
    #pragma unroll
    for (int i = 0; i < 8; ++i) {
      int v = tid + i * 256;
      int r = v >> 3, vc = v & 7;
      *(bf16x8*)&Bs[r][vc * 8] = *(const bf16x8*)(rt + (size_t)r * DIM + k0 + vc * 8);
    }
    __syncthreads();
    #pragma unroll
    for (int ks = 0; ks < 2; ++ks) {
      int kk = ks * 32 + q * 8;
      bf16x8 a[4], b[4];
      #pragma unroll
      for (int mi = 0; mi < 4; ++mi) a[mi] = *(bf16x8*)&As[mi * 16 + lr][kk];
      #pragma unroll
      for (int ni = 0; ni < 4; ++ni) b[ni] = *(bf16x8*)&Bs[w * 64 + ni * 16 + lr][kk];
      #pragma unroll
      for (int mi = 0; mi < 4; ++mi)
        #pragma unroll
        for (int ni = 0; ni < 4; ++ni)
          acc[mi][ni] = __builtin_amdgcn_mfma_f32_16x16x32_bf16(a[mi], b[ni], acc[mi][ni], 0, 0, 0);
    }
    __syncthreads();
  }

  float ps[4][4];
  #pragma unroll
  for (int mi = 0; mi < 4; ++mi)
    #pragma unroll
    for (int rg = 0; rg < 4; ++rg) {
      float s = acc[mi][0][rg] * acc[mi][0][rg] + acc[mi][1][rg] * acc[mi][1][rg]
              + acc[mi][2][rg] * acc[mi][2][rg] + acc[mi][3][rg] * acc[mi][3][rg];
      #pragma unroll
      for (int m = 1; m < 16; m <<= 1) s += __shfl_xor(s, m);
      ps[mi][rg] = s;
    }
  if (lr == 0) {
    #pragma unroll
    for (int mi = 0; mi < 4; ++mi)
      #pragma unroll
      for (int rg = 0; rg < 4; ++rg)
        ssum[w][mi * 16 + q * 4 + rg] = ps[mi][rg];
  }
  __syncthreads();

  #pragma unroll
  for (int mi = 0; mi < 4; ++mi)
    #pragma unroll
    for (int rg = 0; rg < 4; ++rg) {
      int r = mi * 16 + q * 4 + rg;
      float tot = ssum[0][r] + ssum[1][r] + ssum[2][r] + ssum[3][r];
      float inv = 1.0f / fmaxf(sqrtf(tot), 1e-12f);
      #pragma unroll
      for (int ni = 0; ni < 4; ++ni) {
        float val = acc[mi][ni][rg] * inv;
        sx[(size_t)(m0 + r) * SKDIM + w * 64 + ni * 16 + lr] = f2bf(val);
      }
    }
}

// K3 v4: sim row-max. 512 threads, 8 waves (2 wr x 4 wc), wave tile 128x64.
// LDS: 4 slots x (A[256][32] + B[256][32]) bf16 = 128KB.
// Single-barrier pipelined iteration:
//   vmcnt(8 counted); s_barrier; STAGE(t+3); ds_read(t); MFMA(t); fold; lgkm(0)
// Slot-reuse protocol: reads of tile s drain (lgkm 0) before barrier(s+1);
// STAGE(s+4) (which overwrites slot s&3) issues only after barrier(s+1).
// Swizzle: 16B-slot ^= (row>>1)&3 — each 16-lane phase covers all 8 bank
// quads at 2 lanes/quad (conflict-free). Applied to global SOURCE on stage
// (LDS dest linear, required by global_load_lds) and to ds_read address.
__launch_bounds__(512, 2)
__global__ void gemm_sim(const unsigned short* __restrict__ sx,
                         const unsigned short* __restrict__ bufb,
                         float* __restrict__ partial) {
  __shared__ __align__(16) char lb[131072];

  // XCD-chunked swizzle (256 blocks = 8 XCDs x 32), m-fastest inner so the
  // co-resident m-blocks of one n-chunk co-read B via their XCD's L2.
  const int gid = blockIdx.x;
  const int logical = (gid & 7) * 32 + (gid >> 3);
  const int mt = logical & 7;        // 0..7 m-tile (256 rows)
  const int nc = logical >> 3;       // 0..31 n-chunk (4096 cols)
  const int m0 = mt * 256;
  const int ncbase = nc * (NT_PER * 256);

  const int tid = threadIdx.x;
  const int w = tid >> 6, l = tid & 63;
  const int wr = w >> 2, wc = w & 3;        // wave grid 2 x 4
  const int lr = l & 15, q = l >> 4;

  // staging: thread covers (row = j*128 + srow, 16B slot tid&3); source col
  // pre-swizzled by (row>>1)&3 = (srow>>1)&3 (j*128 contributes 0 mod 4).
  const int srow = tid >> 2;                              // 0..127
  const int scol = ((tid & 3) ^ ((srow >> 1) & 3)) * 8;   // source col (elems)
  // read-side swizzle: frag rows are (base mult of 16) + lr -> key (lr>>1)&3
  const int axor = (q ^ ((lr >> 1) & 3)) << 4;

  f32x4 acc[8][4] = {};
  float rm[8][4];
  #pragma unroll
  for (int mi = 0; mi < 8; ++mi)
    #pragma unroll
    for (int rg = 0; rg < 4; ++rg) rm[mi][rg] = -3.0e38f;

#define STAGE(u) do {                                                          \
    const int s_ = (u) & 3;                                                    \
    const int k0_ = ((u) & 7) * 32;                                            \
    const int n0_ = ncbase + ((u) >> 3) * 256;                                 \
    char* dA_ = lb + s_ * 32768;                                               \
    char* dB_ = dA_ + 16384;                                                   \
    _Pragma("unroll")                                                          \
    for (int j_ = 0; j_ < 2; ++j_) {                                           \
      const int row_ = j_ * 128 + srow;                                        \
      const unsigned short* ga_ = sx + (size_t)(m0 + row_) * SKDIM + k0_ + scol; \
      __builtin_amdgcn_global_load_lds(                                        \
          (const __attribute__((address_space(1))) unsigned int*)ga_,          \
          (__attribute__((address_space(3))) unsigned int*)(dA_ + j_ * 8192 + tid * 16), \
          16, 0, 0);                                                           \
      const unsigned short* gb_ = bufb + (size_t)(n0_ + row_) * SKDIM + k0_ + scol; \
      __builtin_amdgcn_global_load_lds(                                        \
          (const __attribute__((address_space(1))) unsigned int*)gb_,          \
          (__attribute__((address_space(3))) unsigned int*)(dB_ + j_ * 8192 + tid * 16), \
          16, 0, 0);                                                           \
    }                                                                          \
  } while (0)

  // prologue: 3 tiles in flight
  STAGE(0); STAGE(1); STAGE(2);

  for (int t = 0; t < NITER; ++t) {
    const int rem = (NITER - 1) - t;
    // slot t complete when only STAGEs t+1, t+2 remain in flight (4 loads each)
    if (rem >= 2) {
      asm volatile("s_waitcnt vmcnt(8)" ::: "memory");
    } else if (rem == 1) {
      asm volatile("s_waitcnt vmcnt(4)" ::: "memory");
    } else {
      asm volatile("s_waitcnt vmcnt(0)" ::: "memory");
    }
    asm volatile("s_barrier" ::: "memory");  // slot t staged by ALL waves; all
                                             // reads of tile t-1 drained

    if (t + 3 < NITER) STAGE(t + 3);         // overwrites slot (t-1)&3 — safe

    const int soff = (t & 3) * 32768;
    const char* pa = lb + soff + (wr * 128 + lr) * 64 + axor;
    const char* pb = lb + soff + 16384 + (wc * 64 + lr) * 64 + axor;
    bf16x8 b[4], a[8];
    #pragma unroll
    for (int ni = 0; ni < 4; ++ni) b[ni] = *(const bf16x8*)(pb + ni * 1024);
    #pragma unroll
    for (int mi = 0; mi < 8; ++mi) a[mi] = *(const bf16x8*)(pa + mi * 1024);

    // compiler inserts progressive counted lgkmcnt before dependent MFMAs
    __builtin_amdgcn_s_setprio(1);
    #pragma unroll
    for (int mi = 0; mi < 8; ++mi)
      #pragma unroll
      for (int ni = 0; ni < 4; ++ni)
        acc[mi][ni] = __builtin_amdgcn_mfma_f32_16x16x32_bf16(a[mi], b[ni], acc[mi][ni], 0, 0, 0);
    __builtin_amdgcn_s_setprio(0);

    if ((t & 7) == 7) {  // n-tile complete: fold row-max, reset acc
      #pragma unroll
      for (int mi = 0; mi < 8; ++mi)
        #pragma unroll
        for (int rg = 0; rg < 4; ++rg) {
          float v = fmaxf(fmaxf(acc[mi][0][rg], acc[mi][1][rg]),
                          fmaxf(acc[mi][2][rg], acc[mi][3][rg]));
          rm[mi][rg] = fmaxf(rm[mi][rg], v);
          #pragma unroll
          for (int ni = 0; ni < 4; ++ni) acc[mi][ni][rg] = 0.0f;
        }
    }

    // drain this tile's ds_reads before signaling (slot-reuse protocol)
    asm volatile("s_waitcnt lgkmcnt(0)" ::: "memory");
  }
#undef STAGE

  // epilogue: reduce over the 16 cols held across lr lanes
  #pragma unroll
  for (int mi = 0; mi < 8; ++mi)
    #pragma unroll
    for (int rg = 0; rg < 4; ++rg) {
      float v = rm[mi][rg];
      v = fmaxf(v, __shfl_xor(v, 1));
      v = fmaxf(v, __shfl_xor(v, 2));
      v = fmaxf(v, __shfl_xor(v, 4));
      v = fmaxf(v, __shfl_xor(v, 8));
      rm[mi][rg] = v;
    }

  float* rmaxs = (float*)lb;   // reuse staging LDS: [4][256]
  asm volatile("s_barrier" ::: "memory");   // all tiles done before LDS reuse
  if (lr == 0) {
    #pragma unroll
    for (int mi = 0; mi < 8; ++mi)
      #pragma unroll
      for (int rg = 0; rg < 4; ++rg)
        rmaxs[wc * 256 + wr * 128 + mi * 16 + q * 4 + rg] = rm[mi][rg];
  }
  __syncthreads();
  if (tid < 256) {
    float v = fmaxf(fmaxf(rmaxs[tid], rmaxs[256 + tid]),
                    fmaxf(rmaxs[512 + tid], rmaxs[768 + tid]));
    partial[(size_t)(m0 + tid) * NGROUPS + nc] = v;
  }
}

// K4: out[r] = 1 - max over 32 partials. 2 rows per 64-thread block.
__global__ void reduce_max(const float* __restrict__ partial, float* __restrict__ out) {
  const int r = blockIdx.x * 2 + (threadIdx.x >> 5);
  const int c = threadIdx.x & 31;
  float m = partial[(size_t)r * NGROUPS + c];
  #pragma unroll
  for (int s = 1; s < 32; s <<= 1) m = fmaxf(m, __shfl_xor(m, s));
  if (c == 0) out[r] = 1.0f - m;
}

extern "C" void kernel_launch(void* const* d_in, const int* in_sizes, int n_in,
                              void* d_out, int out_size, void* d_ws, size_t ws_size,
                              hipStream_t stream) {
  const float* x   = (const float*)d_in[0];   // [2048, 2048]
  const float* R   = (const float*)d_in[1];   // [2048, 256]
  const float* buf = (const float*)d_in[2];   // [131072, 256]
  float* out = (float*)d_out;                  // [2048]

  char* ws = (char*)d_ws;
  // ws layout: rt 1MB | buf_bf 64MB | sx_bf 1MB | partial 256KB
  unsigned short* rt   = (unsigned short*)(ws);
  unsigned short* bufb = (unsigned short*)(ws + (1ull << 20));
  unsigned short* sxb  = (unsigned short*)(ws + (1ull << 20) + (64ull << 20));
  float*          part = (float*)         (ws + (1ull << 20) + (64ull << 20) + (1ull << 20));

  transpose_R<<<dim3((DIM * SKDIM) / 256), dim3(256), 0, stream>>>(R, rt);
  conv_buf<<<dim3(2048), dim3(256), 0, stream>>>(buf, bufb);
  gemm_sketch<<<dim3(BROWS / 64), dim3(256), 0, stream>>>(x, rt, sxb);
  gemm_sim<<<dim3(256), dim3(512), 0, stream>>>(sxb, bufb, part);
  reduce_max<<<dim3(BROWS / 2), dim3(64), 0, stream>>>(part, out);
}

// Round 5
// 183.341 us; speedup vs baseline: 2.1505x; 1.1647x over previous
//
#include <hip/hip_runtime.h>
#include <hip/hip_bf16.h>

// Problem: B=2048, DIM=2048, SKETCH=256, SIZE=131072
//   sx = normalize_rows(x @ R); out = 1 - max_row(sx @ buffer^T)

#define BROWS 2048
#define DIM   2048
#define SKDIM 256
#define NBUF  131072

// gemm_sim v5: 256 blocks, 512 thr (8 waves, 2x4), block tile 256 rows x
// (16 n-tiles x 256 cols), BK=64 K-tiles (4 per n-tile), m201-style 4-phase
// windows, 2 LDS K-tile slots (dbuf), counted vmcnt(2) once per window.
#define NGROUPS 32            // n-chunks (4096 cols each)
#define NT_PER  16            // 256-col n-tiles per block
#define GMAX    (NT_PER * 4 - 1)   // 63 K-tile windows

typedef __attribute__((ext_vector_type(4))) float f32x4;
typedef __attribute__((ext_vector_type(8))) short bf16x8;
typedef __attribute__((ext_vector_type(4))) short bf16x4;

static __device__ inline unsigned short f2bf(float f) {
  unsigned u = __float_as_uint(f);
  unsigned r = u + 0x7FFFu + ((u >> 16) & 1u);  // round-to-nearest-even
  return (unsigned short)(r >> 16);
}

static __device__ inline bf16x8 cvt8(const float* __restrict__ p) {
  f32x4 a = *(const f32x4*)p;
  f32x4 b = *(const f32x4*)(p + 4);
  bf16x8 r;
  r[0] = (short)f2bf(a[0]); r[1] = (short)f2bf(a[1]);
  r[2] = (short)f2bf(a[2]); r[3] = (short)f2bf(a[3]);
  r[4] = (short)f2bf(b[0]); r[5] = (short)f2bf(b[1]);
  r[6] = (short)f2bf(b[2]); r[7] = (short)f2bf(b[3]);
  return r;
}

// K0: RT_bf[n][k] = bf16(R[k][n])   (256 x 2048)
__global__ void transpose_R(const float* __restrict__ R, unsigned short* __restrict__ rt) {
  int idx = blockIdx.x * 256 + threadIdx.x;
  int k = idx >> 8, n = idx & 255;
  rt[n * DIM + k] = f2bf(R[idx]);
}

// K1+K2 fused: blocks 0..31 = gemm_sketch (normalize(x@R) -> sx bf16);
// blocks 32..2079 = conv_buf (f32 -> bf16, 131072x256). The BW-bound conv
// hides the latency-bound 32-block sketch.
__launch_bounds__(256)
__global__ void sketch_conv(const float* __restrict__ x, const unsigned short* __restrict__ rt,
                            unsigned short* __restrict__ sx,
                            const float* __restrict__ bufin, unsigned short* __restrict__ outb) {
  __shared__ unsigned short As[64][72];
  __shared__ unsigned short Bs[256][72];
  __shared__ float ssum[4][64];

  if (blockIdx.x >= 32) {
    // ---- conv path ----
    const int nvec = (NBUF * SKDIM) / 4;
    int stride = 2048 * 256;
    for (int i = (blockIdx.x - 32) * 256 + threadIdx.x; i < nvec; i += stride) {
      f32x4 v = ((const f32x4*)bufin)[i];
      bf16x4 r;
      r[0] = (short)f2bf(v[0]); r[1] = (short)f2bf(v[1]);
      r[2] = (short)f2bf(v[2]); r[3] = (short)f2bf(v[3]);
      ((bf16x4*)outb)[i] = r;
    }
    return;
  }

  // ---- sketch path (validated R0-R3) ----
  const int m0 = blockIdx.x * 64;
  const int tid = threadIdx.x;
  const int w = tid >> 6, l = tid & 63;
  const int lr = l & 15, q = l >> 4;

  f32x4 acc[4][4] = {};

  for (int k0 = 0; k0 < DIM; k0 += 64) {
    #pragma unroll
    for (int i = 0; i < 2; ++i) {
      int v = tid + i * 256;
      int r = v >> 3, vc = v & 7;
      *(bf16x8*)&As[r][vc * 8] = cvt8(x + (size_t)(m0 + r) * DIM + k0 + vc * 8);
    }
    #pragma unroll
    for (int i = 0; i < 8; ++i) {
      int v = tid + i * 256;
      int r = v >> 3, vc = v & 7;
      *(bf16x8*)&Bs[r][vc * 8] = *(const bf16x8*)(rt + (size_t)r * DIM + k0 + vc * 8);
    }
    __syncthreads();
    #pragma unroll
    for (int ks = 0; ks < 2; ++ks) {
      int kk = ks * 32 + q * 8;
      bf16x8 a[4], b[4];
      #pragma unroll
      for (int mi = 0; mi < 4; ++mi) a[mi] = *(bf16x8*)&As[mi * 16 + lr][kk];
      #pragma unroll
      for (int ni = 0; ni < 4; ++ni) b[ni] = *(bf16x8*)&Bs[w * 64 + ni * 16 + lr][kk];
      #pragma unroll
      for (int mi = 0; mi < 4; ++mi)
        #pragma unroll
        for (int ni = 0; ni < 4; ++ni)
          acc[mi][ni] = __builtin_amdgcn_mfma_f32_16x16x32_bf16(a[mi], b[ni], acc[mi][ni], 0, 0, 0);
    }
    __syncthreads();
  }

  float ps[4][4];
  #pragma unroll
  for (int mi = 0; mi < 4; ++mi)
    #pragma unroll
    for (int rg = 0; rg < 4; ++rg) {
      float s = acc[mi][0][rg] * acc[mi][0][rg] + acc[mi][1][rg] * acc[mi][1][rg]
              + acc[mi][2][rg] * acc[mi][2][rg] + acc[mi][3][rg] * acc[mi][3][rg];
      #pragma unroll
      for (int m = 1; m < 16; m <<= 1) s += __shfl_xor(s, m);
      ps[mi][rg] = s;
    }
  if (lr == 0) {
    #pragma unroll
    for (int mi = 0; mi < 4; ++mi)
      #pragma unroll
      for (int rg = 0; rg < 4; ++rg)
        ssum[w][mi * 16 + q * 4 + rg] = ps[mi][rg];
  }
  __syncthreads();

  #pragma unroll
  for (int mi = 0; mi < 4; ++mi)
    #pragma unroll
    for (int rg = 0; rg < 4; ++rg) {
      int r = mi * 16 + q * 4 + rg;
      float tot = ssum[0][r] + ssum[1][r] + ssum[2][r] + ssum[3][r];
      float inv = 1.0f / fmaxf(sqrtf(tot), 1e-12f);
      #pragma unroll
      for (int ni = 0; ni < 4; ++ni) {
        float val = acc[mi][ni][rg] * inv;
        sx[(size_t)(m0 + r) * SKDIM + w * 64 + ni * 16 + lr] = f2bf(val);
      }
    }
}

// K3 v5: 8-phase (m201) schedule. LDS slots: slot s (s=0,1) at s*64KB:
// A[256][64] bf16 (32KB) then B[256][64] (32KB). Row stride 128B; 8 16B
// col-slots per row, XOR-swizzled by (row>>1)&7 (2 lanes/bank-quad = free).
// Window g (K-tile): 4 phases; phase = {ds_read frag subtile; stage one
// half-tile; barrier; lgkm0; setprio1 + 16 MFMA + setprio0; barrier}.
// Stage order: p0 Bh0(g+1), p1 Bh1(g+1), p2 Ah1(g+1), p3 Ah0(g+2).
// vmcnt(2) once per window at p3 (tile g+1 landed; Ah0(g+2) may fly).
__launch_bounds__(512, 2)
__global__ void gemm_sim(const unsigned short* __restrict__ sx,
                         const unsigned short* __restrict__ bufb,
                         float* __restrict__ partial) {
  __shared__ __align__(16) char lb[131072];

  const int gid = blockIdx.x;
  const int logical = (gid & 7) * 32 + (gid >> 3);
  const int mt = logical & 7;        // 0..7 m-tile (256 rows)
  const int nc = logical >> 3;       // 0..31 n-chunk (4096 cols)
  const int m0 = mt * 256;
  const int ncbase = nc * (NT_PER * 256);

  const int tid = threadIdx.x;
  const int w = tid >> 6, l = tid & 63;
  const int wr = w >> 2, wc = w & 3;        // wave grid 2 x 4
  const int lr = l & 15, q = l >> 4;

  // stage source pre-swizzle: LDS linear dest (row = j*64 + (tid>>3),
  // slot = tid&7); global col-slot = (tid&7) ^ ((tid>>4)&7)
  const int scol = ((tid & 7) ^ ((tid >> 4) & 7)) * 8;   // elements
  // read swizzle: slot = (ks*4+q) ^ ((lr>>1)&7); byte-in-row offsets:
  const int offk0 = ((q ^ ((lr >> 1) & 7)) << 4);
  const int offk1 = offk0 ^ 64;

  f32x4 acc[8][4] = {};
  float rm[8][4];
  #pragma unroll
  for (int mi = 0; mi < 8; ++mi)
    #pragma unroll
    for (int rg = 0; rg < 4; ++rg) rm[mi][rg] = -3.0e38f;

  // STAGEH: one 16KB half-tile (2 global_load_lds of 16B per thread)
#define STAGEH(tile, isB, half) do {                                           \
    const int t_ = (tile);                                                     \
    char* dst_ = lb + ((t_) & 1) * 65536 + (isB) * 32768 + (half) * 16384      \
               + tid * 16;                                                     \
    const unsigned short* src_ = (isB)                                         \
      ? (bufb + (size_t)(ncbase + (t_ >> 2) * 256 + (half) * 128 + (tid >> 3)) * SKDIM \
              + ((t_) & 3) * 64 + scol)                                        \
      : (sx + (size_t)(m0 + (half) * 128 + (tid >> 3)) * SKDIM                 \
            + ((t_) & 3) * 64 + scol);                                         \
    __builtin_amdgcn_global_load_lds(                                          \
        (const __attribute__((address_space(1))) unsigned int*)src_,           \
        (__attribute__((address_space(3))) unsigned int*)dst_, 16, 0, 0);      \
    __builtin_amdgcn_global_load_lds(                                          \
        (const __attribute__((address_space(1))) unsigned int*)(src_ + 64 * SKDIM), \
        (__attribute__((address_space(3))) unsigned int*)(dst_ + 8192), 16, 0, 0); \
  } while (0)

  // prologue: tile0 fully + Ah0(1); per-thread in-flight = 10 loads
  STAGEH(0, 0, 0);
  STAGEH(0, 0, 1);
  STAGEH(0, 1, 0);
  STAGEH(0, 1, 1);
  STAGEH(1, 0, 0);
  asm volatile("s_waitcnt vmcnt(2)" ::: "memory");   // tile0 landed
  __builtin_amdgcn_s_barrier();

  bf16x8 aL[4][2], aH[4][2], bL[2][2], bH[2][2];

  for (int g = 0; g <= GMAX; ++g) {
    const int s = g & 1;
    const char* pA = lb + s * 65536 + (wr * 128 + lr) * 128;
    const char* pB = lb + s * 65536 + 32768 + (wc * 64 + lr) * 128;
    const bool st1 = (g + 1 <= GMAX);

    // ---------- phase 0: read aL + bL; stage Bh0(g+1); MFMA Q(lo,lo) ----------
    #pragma unroll
    for (int mi = 0; mi < 4; ++mi) {
      aL[mi][0] = *(const bf16x8*)(pA + mi * 2048 + offk0);
      aL[mi][1] = *(const bf16x8*)(pA + mi * 2048 + offk1);
    }
    #pragma unroll
    for (int ni = 0; ni < 2; ++ni) {
      bL[ni][0] = *(const bf16x8*)(pB + ni * 2048 + offk0);
      bL[ni][1] = *(const bf16x8*)(pB + ni * 2048 + offk1);
    }
    if (st1) STAGEH(g + 1, 1, 0);
    __builtin_amdgcn_s_barrier();
    asm volatile("s_waitcnt lgkmcnt(0)" ::: "memory");
    __builtin_amdgcn_s_setprio(1);
    #pragma unroll
    for (int mi = 0; mi < 4; ++mi)
      #pragma unroll
      for (int ni = 0; ni < 2; ++ni) {
        acc[mi][ni] = __builtin_amdgcn_mfma_f32_16x16x32_bf16(aL[mi][0], bL[ni][0], acc[mi][ni], 0, 0, 0);
        acc[mi][ni] = __builtin_amdgcn_mfma_f32_16x16x32_bf16(aL[mi][1], bL[ni][1], acc[mi][ni], 0, 0, 0);
      }
    __builtin_amdgcn_s_setprio(0);
    __builtin_amdgcn_s_barrier();

    // ---------- phase 1: read bH; stage Bh1(g+1); MFMA Q(lo,hi) ----------
    #pragma unroll
    for (int ni = 0; ni < 2; ++ni) {
      bH[ni][0] = *(const bf16x8*)(pB + (ni + 2) * 2048 + offk0);
      bH[ni][1] = *(const bf16x8*)(pB + (ni + 2) * 2048 + offk1);
    }
    if (st1) STAGEH(g + 1, 1, 1);
    __builtin_amdgcn_s_barrier();
    asm volatile("s_waitcnt lgkmcnt(0)" ::: "memory");
    __builtin_amdgcn_s_setprio(1);
    #pragma unroll
    for (int mi = 0; mi < 4; ++mi)
      #pragma unroll
      for (int ni = 0; ni < 2; ++ni) {
        acc[mi][ni + 2] = __builtin_amdgcn_mfma_f32_16x16x32_bf16(aL[mi][0], bH[ni][0], acc[mi][ni + 2], 0, 0, 0);
        acc[mi][ni + 2] = __builtin_amdgcn_mfma_f32_16x16x32_bf16(aL[mi][1], bH[ni][1], acc[mi][ni + 2], 0, 0, 0);
      }
    __builtin_amdgcn_s_setprio(0);
    __builtin_amdgcn_s_barrier();

    // ---------- phase 2: read aH; stage Ah1(g+1); MFMA Q(hi,lo) ----------
    #pragma unroll
    for (int mi = 0; mi < 4; ++mi) {
      aH[mi][0] = *(const bf16x8*)(pA + (mi + 4) * 2048 + offk0);
      aH[mi][1] = *(const bf16x8*)(pA + (mi + 4) * 2048 + offk1);
    }
    if (st1) STAGEH(g + 1, 0, 1);
    __builtin_amdgcn_s_barrier();
    asm volatile("s_waitcnt lgkmcnt(0)" ::: "memory");
    __builtin_amdgcn_s_setprio(1);
    #pragma unroll
    for (int mi = 0; mi < 4; ++mi)
      #pragma unroll
      for (int ni = 0; ni < 2; ++ni) {
        acc[mi + 4][ni] = __builtin_amdgcn_mfma_f32_16x16x32_bf16(aH[mi][0], bL[ni][0], acc[mi + 4][ni], 0, 0, 0);
        acc[mi + 4][ni] = __builtin_amdgcn_mfma_f32_16x16x32_bf16(aH[mi][1], bL[ni][1], acc[mi + 4][ni], 0, 0, 0);
      }
    __builtin_amdgcn_s_setprio(0);
    __builtin_amdgcn_s_barrier();

    // ---------- phase 3: stage Ah0(g+2); MFMA Q(hi,hi); fold; vmcnt ----------
    if (g + 2 <= GMAX) STAGEH(g + 2, 0, 0);
    __builtin_amdgcn_s_barrier();
    __builtin_amdgcn_s_setprio(1);
    #pragma unroll
    for (int mi = 0; mi < 4; ++mi)
      #pragma unroll
      for (int ni = 0; ni < 2; ++ni) {
        acc[mi + 4][ni + 2] = __builtin_amdgcn_mfma_f32_16x16x32_bf16(aH[mi][0], bH[ni][0], acc[mi + 4][ni + 2], 0, 0, 0);
        acc[mi + 4][ni + 2] = __builtin_amdgcn_mfma_f32_16x16x32_bf16(aH[mi][1], bH[ni][1], acc[mi + 4][ni + 2], 0, 0, 0);
      }
    __builtin_amdgcn_s_setprio(0);

    if ((g & 3) == 3) {  // n-tile complete: fold row-max, reset acc
      #pragma unroll
      for (int mi = 0; mi < 8; ++mi)
        #pragma unroll
        for (int rg = 0; rg < 4; ++rg) {
          float v = fmaxf(fmaxf(acc[mi][0][rg], acc[mi][1][rg]),
                          fmaxf(acc[mi][2][rg], acc[mi][3][rg]));
          rm[mi][rg] = fmaxf(rm[mi][rg], v);
          #pragma unroll
          for (int ni = 0; ni < 4; ++ni) acc[mi][ni][rg] = 0.0f;
        }
    }

    if (g + 2 <= GMAX) {
      asm volatile("s_waitcnt vmcnt(2)" ::: "memory");   // tile g+1 landed
    } else {
      asm volatile("s_waitcnt vmcnt(0)" ::: "memory");   // tail drain
    }
    __builtin_amdgcn_s_barrier();
  }
#undef STAGEH

  // epilogue: reduce over the 16 cols held across lr lanes
  #pragma unroll
  for (int mi = 0; mi < 8; ++mi)
    #pragma unroll
    for (int rg = 0; rg < 4; ++rg) {
      float v = rm[mi][rg];
      v = fmaxf(v, __shfl_xor(v, 1));
      v = fmaxf(v, __shfl_xor(v, 2));
      v = fmaxf(v, __shfl_xor(v, 4));
      v = fmaxf(v, __shfl_xor(v, 8));
      rm[mi][rg] = v;
    }

  float* rmaxs = (float*)lb;   // reuse staging LDS: [4][256]
  __syncthreads();             // full drain (vmcnt+lgkm) before LDS reuse
  if (lr == 0) {
    #pragma unroll
    for (int mi = 0; mi < 8; ++mi)
      #pragma unroll
      for (int rg = 0; rg < 4; ++rg)
        rmaxs[wc * 256 + wr * 128 + mi * 16 + q * 4 + rg] = rm[mi][rg];
  }
  __syncthreads();
  if (tid < 256) {
    float v = fmaxf(fmaxf(rmaxs[tid], rmaxs[256 + tid]),
                    fmaxf(rmaxs[512 + tid], rmaxs[768 + tid]));
    partial[(size_t)(m0 + tid) * NGROUPS + nc] = v;
  }
}

// K4: out[r] = 1 - max over 32 partials. 2 rows per 64-thread block.
__global__ void reduce_max(const float* __restrict__ partial, float* __restrict__ out) {
  const int r = blockIdx.x * 2 + (threadIdx.x >> 5);
  const int c = threadIdx.x & 31;
  float m = partial[(size_t)r * NGROUPS + c];
  #pragma unroll
  for (int s = 1; s < 32; s <<= 1) m = fmaxf(m, __shfl_xor(m, s));
  if (c == 0) out[r] = 1.0f - m;
}

extern "C" void kernel_launch(void* const* d_in, const int* in_sizes, int n_in,
                              void* d_out, int out_size, void* d_ws, size_t ws_size,
                              hipStream_t stream) {
  const float* x   = (const float*)d_in[0];   // [2048, 2048]
  const float* R   = (const float*)d_in[1];   // [2048, 256]
  const float* buf = (const float*)d_in[2];   // [131072, 256]
  float* out = (float*)d_out;                  // [2048]

  char* ws = (char*)d_ws;
  // ws layout: rt 1MB | buf_bf 64MB | sx_bf 1MB | partial 256KB
  unsigned short* rt   = (unsigned short*)(ws);
  unsigned short* bufb = (unsigned short*)(ws + (1ull << 20));
  unsigned short* sxb  = (unsigned short*)(ws + (1ull << 20) + (64ull << 20));
  float*          part = (float*)         (ws + (1ull << 20) + (64ull << 20) + (1ull << 20));

  transpose_R<<<dim3((DIM * SKDIM) / 256), dim3(256), 0, stream>>>(R, rt);
  sketch_conv<<<dim3(2080), dim3(256), 0, stream>>>(x, rt, sxb, buf, bufb);
  gemm_sim<<<dim3(256), dim3(512), 0, stream>>>(sxb, bufb, part);
  reduce_max<<<dim3(BROWS / 2), dim3(64), 0, stream>>>(part, out);
}

// Round 6
// 179.989 us; speedup vs baseline: 2.1906x; 1.0186x over previous
//
#include <hip/hip_runtime.h>
#include <hip/hip_bf16.h>

// Problem: B=2048, DIM=2048, SKETCH=256, SIZE=131072
//   sx = normalize_rows(x @ R); out = 1 - max_row(sx @ buffer^T)

#define BROWS 2048
#define DIM   2048
#define SKDIM 256
#define NBUF  131072

// gemm_sim v7: 256 blocks, 512 thr (8 waves, 2x4), block tile 256 rows x
// (16 n-tiles x 256 cols), BK=64 windows, 2-slot LDS double buffer,
// ONE vmcnt(0)+s_barrier per window (classic dbuf protocol), compiler-
// scheduled ds_read/MFMA interleave inside the window.
#define NGROUPS 32            // n-chunks (4096 cols each)
#define NT_PER  16            // 256-col n-tiles per block
#define GMAX    (NT_PER * 4 - 1)   // 63 BK=64 windows

typedef __attribute__((ext_vector_type(4))) float f32x4;
typedef __attribute__((ext_vector_type(8))) short bf16x8;
typedef __attribute__((ext_vector_type(4))) short bf16x4;

static __device__ inline unsigned short f2bf(float f) {
  unsigned u = __float_as_uint(f);
  unsigned r = u + 0x7FFFu + ((u >> 16) & 1u);  // round-to-nearest-even
  return (unsigned short)(r >> 16);
}

static __device__ inline bf16x8 cvt8(const float* __restrict__ p) {
  f32x4 a = *(const f32x4*)p;
  f32x4 b = *(const f32x4*)(p + 4);
  bf16x8 r;
  r[0] = (short)f2bf(a[0]); r[1] = (short)f2bf(a[1]);
  r[2] = (short)f2bf(a[2]); r[3] = (short)f2bf(a[3]);
  r[4] = (short)f2bf(b[0]); r[5] = (short)f2bf(b[1]);
  r[6] = (short)f2bf(b[2]); r[7] = (short)f2bf(b[3]);
  return r;
}

// K0: RT_bf[n][k] = bf16(R[k][n])   (256 x 2048)
__global__ void transpose_R(const float* __restrict__ R, unsigned short* __restrict__ rt) {
  int idx = blockIdx.x * 256 + threadIdx.x;
  int k = idx >> 8, n = idx & 255;
  rt[n * DIM + k] = f2bf(R[idx]);
}

// K1+K2 fused: blocks 0..31 = gemm_sketch; blocks 32..2079 = conv_buf.
__launch_bounds__(256)
__global__ void sketch_conv(const float* __restrict__ x, const unsigned short* __restrict__ rt,
                            unsigned short* __restrict__ sx,
                            const float* __restrict__ bufin, unsigned short* __restrict__ outb) {
  __shared__ unsigned short As[64][72];
  __shared__ unsigned short Bs[256][72];
  __shared__ float ssum[4][64];

  if (blockIdx.x >= 32) {
    // ---- conv path ----
    const int nvec = (NBUF * SKDIM) / 4;
    int stride = 2048 * 256;
    for (int i = (blockIdx.x - 32) * 256 + threadIdx.x; i < nvec; i += stride) {
      f32x4 v = ((const f32x4*)bufin)[i];
      bf16x4 r;
      r[0] = (short)f2bf(v[0]); r[1] = (short)f2bf(v[1]);
      r[2] = (short)f2bf(v[2]); r[3] = (short)f2bf(v[3]);
      ((bf16x4*)outb)[i] = r;
    }
    return;
  }

  // ---- sketch path (validated R0-R4) ----
  const int m0 = blockIdx.x * 64;
  const int tid = threadIdx.x;
  const int w = tid >> 6, l = tid & 63;
  const int lr = l & 15, q = l >> 4;

  f32x4 acc[4][4] = {};

  for (int k0 = 0; k0 < DIM; k0 += 64) {
    #pragma unroll
    for (int i = 0; i < 2; ++i) {
      int v = tid + i * 256;
      int r = v >> 3, vc = v & 7;
      *(bf16x8*)&As[r][vc * 8] = cvt8(x + (size_t)(m0 + r) * DIM + k0 + vc * 8);
    }
    #pragma unroll
    for (int i = 0; i < 8; ++i) {
      int v = tid + i * 256;
      int r = v >> 3, vc = v & 7;
      *(bf16x8*)&Bs[r][vc * 8] = *(const bf16x8*)(rt + (size_t)r * DIM + k0 + vc * 8);
    }
    __syncthreads();
    #pragma unroll
    for (int ks = 0; ks < 2; ++ks) {
      int kk = ks * 32 + q * 8;
      bf16x8 a[4], b[4];
      #pragma unroll
      for (int mi = 0; mi < 4; ++mi) a[mi] = *(bf16x8*)&As[mi * 16 + lr][kk];
      #pragma unroll
      for (int ni = 0; ni < 4; ++ni) b[ni] = *(bf16x8*)&Bs[w * 64 + ni * 16 + lr][kk];
      #pragma unroll
      for (int mi = 0; mi < 4; ++mi)
        #pragma unroll
        for (int ni = 0; ni < 4; ++ni)
          acc[mi][ni] = __builtin_amdgcn_mfma_f32_16x16x32_bf16(a[mi], b[ni], acc[mi][ni], 0, 0, 0);
    }
    __syncthreads();
  }

  float ps[4][4];
  #pragma unroll
  for (int mi = 0; mi < 4; ++mi)
    #pragma unroll
    for (int rg = 0; rg < 4; ++rg) {
      float s = acc[mi][0][rg] * acc[mi][0][rg] + acc[mi][1][rg] * acc[mi][1][rg]
              + acc[mi][2][rg] * acc[mi][2][rg] + acc[mi][3][rg] * acc[mi][3][rg];
      #pragma unroll
      for (int m = 1; m < 16; m <<= 1) s += __shfl_xor(s, m);
      ps[mi][rg] = s;
    }
  if (lr == 0) {
    #pragma unroll
    for (int mi = 0; mi < 4; ++mi)
      #pragma unroll
      for (int rg = 0; rg < 4; ++rg)
        ssum[w][mi * 16 + q * 4 + rg] = ps[mi][rg];
  }
  __syncthreads();

  #pragma unroll
  for (int mi = 0; mi < 4; ++mi)
    #pragma unroll
    for (int rg = 0; rg < 4; ++rg) {
      int r = mi * 16 + q * 4 + rg;
      float tot = ssum[0][r] + ssum[1][r] + ssum[2][r] + ssum[3][r];
      float inv = 1.0f / fmaxf(sqrtf(tot), 1e-12f);
      #pragma unroll
      for (int ni = 0; ni < 4; ++ni) {
        float val = acc[mi][ni][rg] * inv;
        sx[(size_t)(m0 + r) * SKDIM + w * 64 + ni * 16 + lr] = f2bf(val);
      }
    }
}

// K3 v7: sim row-max. 512 threads, 8 waves (2 wr x 4 wc), wave tile 128x64.
// LDS: 2 slots x (A[256][64] + B[256][64]) bf16 = 128KB. Per window g:
//   STAGE tile g+1 -> slot s^1 (8 global_load_lds);
//   ds_read chunk0 (12 b128) ; 32 MFMA ; ds_read chunk1 ; 32 MFMA  (compiler-
//   scheduled counted lgkmcnt — NO mid-window barriers);
//   fold row-max every 4th window;
//   s_waitcnt vmcnt(0) ; s_barrier   <- the ONLY sync per window. It is both
//   the read-gate for tile g+1 (own stage loads drained pre-arrival) and the
//   WAR fence for slot s^1 (own ds_reads drained by MFMA deps pre-arrival).
// Swizzle: 16B col-slot ^= (row>>1)&7, applied to global SOURCE on stage and
// to ds_read address (both-sides, rule #21); frag-row bases are multiples of
// 16 so the read key is (lr>>1)&7 exactly.
__launch_bounds__(512, 2)
__global__ void gemm_sim(const unsigned short* __restrict__ sx,
                         const unsigned short* __restrict__ bufb,
                         float* __restrict__ partial) {
  __shared__ __align__(16) char lb[131072];

  // XCD-chunked swizzle (256 blocks = 8 XCDs x 32), m-fastest inner so the
  // 8 m-blocks sharing one B n-chunk live on the same XCD's L2.
  const int gid = blockIdx.x;
  const int logical = (gid & 7) * 32 + (gid >> 3);
  const int mt = logical & 7;        // 0..7 m-tile (256 rows)
  const int nc = logical >> 3;       // 0..31 n-chunk (4096 cols)
  const int m0 = mt * 256;
  const int ncbase = nc * (NT_PER * 256);

  const int tid = threadIdx.x;
  const int w = tid >> 6, l = tid & 63;
  const int wr = w >> 2, wc = w & 3;        // wave grid 2 x 4
  const int lr = l & 15, q = l >> 4;

  // staging: LDS linear dest (row = half*128 + (tid>>3) (+64 for 2nd load),
  // 16B slot tid&7); global source col-slot pre-swizzled by (row>>1)&7.
  const int scol = ((tid & 7) ^ ((tid >> 4) & 7)) * 8;   // elements
  // read swizzle: chunk-c slot = (c*4+q) ^ ((lr>>1)&7)
  const int off0 = ((q ^ ((lr >> 1) & 7)) << 4);
  const int off1 = off0 ^ 64;

  f32x4 acc[8][4] = {};
  float rm[8][4];
  #pragma unroll
  for (int mi = 0; mi < 8; ++mi)
    #pragma unroll
    for (int rg = 0; rg < 4; ++rg) rm[mi][rg] = -3.0e38f;

#define STAGEH(tile, isB, half) do {                                           \
    const int t_ = (tile);                                                     \
    char* dst_ = lb + ((t_) & 1) * 65536 + (isB) * 32768 + (half) * 16384      \
               + tid * 16;                                                     \
    const unsigned short* src_ = (isB)                                         \
      ? (bufb + (size_t)(ncbase + (t_ >> 2) * 256 + (half) * 128 + (tid >> 3)) * SKDIM \
              + ((t_) & 3) * 64 + scol)                                        \
      : (sx + (size_t)(m0 + (half) * 128 + (tid >> 3)) * SKDIM                 \
            + ((t_) & 3) * 64 + scol);                                         \
    __builtin_amdgcn_global_load_lds(                                          \
        (const __attribute__((address_space(1))) unsigned int*)src_,           \
        (__attribute__((address_space(3))) unsigned int*)dst_, 16, 0, 0);      \
    __builtin_amdgcn_global_load_lds(                                          \
        (const __attribute__((address_space(1))) unsigned int*)(src_ + 64 * SKDIM), \
        (__attribute__((address_space(3))) unsigned int*)(dst_ + 8192), 16, 0, 0); \
  } while (0)

  // prologue: stage tile 0, drain, barrier
  STAGEH(0, 1, 0);
  STAGEH(0, 1, 1);
  STAGEH(0, 0, 0);
  STAGEH(0, 0, 1);
  asm volatile("s_waitcnt vmcnt(0)" ::: "memory");
  __builtin_amdgcn_s_barrier();

  for (int g = 0; g <= GMAX; ++g) {
    const int s = g & 1;
    const char* pA = lb + s * 65536 + (wr * 128 + lr) * 128;
    const char* pB = lb + s * 65536 + 32768 + (wc * 64 + lr) * 128;

    // prefetch next tile into the opposite slot (full-window lead)
    if (g < GMAX) {
      STAGEH(g + 1, 1, 0);
      STAGEH(g + 1, 1, 1);
      STAGEH(g + 1, 0, 0);
      STAGEH(g + 1, 0, 1);
    }

    // ---- chunk 0 (k 0..31): 12 ds_read_b128, 32 independent MFMA ----
    bf16x8 a0[8], b0[4];
    #pragma unroll
    for (int mi = 0; mi < 8; ++mi) a0[mi] = *(const bf16x8*)(pA + mi * 2048 + off0);
    #pragma unroll
    for (int ni = 0; ni < 4; ++ni) b0[ni] = *(const bf16x8*)(pB + ni * 2048 + off0);
    __builtin_amdgcn_s_setprio(1);
    #pragma unroll
    for (int mi = 0; mi < 8; ++mi)
      #pragma unroll
      for (int ni = 0; ni < 4; ++ni)
        acc[mi][ni] = __builtin_amdgcn_mfma_f32_16x16x32_bf16(a0[mi], b0[ni], acc[mi][ni], 0, 0, 0);
    __builtin_amdgcn_s_setprio(0);

    // ---- chunk 1 (k 32..63) ----
    bf16x8 a1[8], b1[4];
    #pragma unroll
    for (int mi = 0; mi < 8; ++mi) a1[mi] = *(const bf16x8*)(pA + mi * 2048 + off1);
    #pragma unroll
    for (int ni = 0; ni < 4; ++ni) b1[ni] = *(const bf16x8*)(pB + ni * 2048 + off1);
    __builtin_amdgcn_s_setprio(1);
    #pragma unroll
    for (int mi = 0; mi < 8; ++mi)
      #pragma unroll
      for (int ni = 0; ni < 4; ++ni)
        acc[mi][ni] = __builtin_amdgcn_mfma_f32_16x16x32_bf16(a1[mi], b1[ni], acc[mi][ni], 0, 0, 0);
    __builtin_amdgcn_s_setprio(0);

    if ((g & 3) == 3) {  // n-tile complete: fold row-max, reset acc
      #pragma unroll
      for (int mi = 0; mi < 8; ++mi)
        #pragma unroll
        for (int rg = 0; rg < 4; ++rg) {
          float v = fmaxf(fmaxf(acc[mi][0][rg], acc[mi][1][rg]),
                          fmaxf(acc[mi][2][rg], acc[mi][3][rg]));
          rm[mi][rg] = fmaxf(rm[mi][rg], v);
          #pragma unroll
          for (int ni = 0; ni < 4; ++ni) acc[mi][ni][rg] = 0.0f;
        }
    }

    // single per-window sync: next tile landed + this tile's reads drained
    asm volatile("s_waitcnt vmcnt(0)" ::: "memory");
    __builtin_amdgcn_s_barrier();
  }
#undef STAGEH

  // epilogue: reduce over the 16 cols held across lr lanes
  #pragma unroll
  for (int mi = 0; mi < 8; ++mi)
    #pragma unroll
    for (int rg = 0; rg < 4; ++rg) {
      float v = rm[mi][rg];
      v = fmaxf(v, __shfl_xor(v, 1));
      v = fmaxf(v, __shfl_xor(v, 2));
      v = fmaxf(v, __shfl_xor(v, 4));
      v = fmaxf(v, __shfl_xor(v, 8));
      rm[mi][rg] = v;
    }

  float* rmaxs = (float*)lb;   // reuse staging LDS: [4][256]
  __syncthreads();
  if (lr == 0) {
    #pragma unroll
    for (int mi = 0; mi < 8; ++mi)
      #pragma unroll
      for (int rg = 0; rg < 4; ++rg)
        rmaxs[wc * 256 + wr * 128 + mi * 16 + q * 4 + rg] = rm[mi][rg];
  }
  __syncthreads();
  if (tid < 256) {
    float v = fmaxf(fmaxf(rmaxs[tid], rmaxs[256 + tid]),
                    fmaxf(rmaxs[512 + tid], rmaxs[768 + tid]));
    partial[(size_t)(m0 + tid) * NGROUPS + nc] = v;
  }
}

// K4: out[r] = 1 - max over 32 partials. 2 rows per 64-thread block.
__global__ void reduce_max(const float* __restrict__ partial, float* __restrict__ out) {
  const int r = blockIdx.x * 2 + (threadIdx.x >> 5);
  const int c = threadIdx.x & 31;
  float m = partial[(size_t)r * NGROUPS + c];
  #pragma unroll
  for (int s = 1; s < 32; s <<= 1) m = fmaxf(m, __shfl_xor(m, s));
  if (c == 0) out[r] = 1.0f - m;
}

extern "C" void kernel_launch(void* const* d_in, const int* in_sizes, int n_in,
                              void* d_out, int out_size, void* d_ws, size_t ws_size,
                              hipStream_t stream) {
  const float* x   = (const float*)d_in[0];   // [2048, 2048]
  const float* R   = (const float*)d_in[1];   // [2048, 256]
  const float* buf = (const float*)d_in[2];   // [131072, 256]
  float* out = (float*)d_out;                  // [2048]

  char* ws = (char*)d_ws;
  // ws layout: rt 1MB | buf_bf 64MB | sx_bf 1MB | partial 256KB
  unsigned short* rt   = (unsigned short*)(ws);
  unsigned short* bufb = (unsigned short*)(ws + (1ull << 20));
  unsigned short* sxb  = (unsigned short*)(ws + (1ull << 20) + (64ull << 20));
  float*          part = (float*)         (ws + (1ull << 20) + (64ull << 20) + (1ull << 20));

  transpose_R<<<dim3((DIM * SKDIM) / 256), dim3(256), 0, stream>>>(R, rt);
  sketch_conv<<<dim3(2080), dim3(256), 0, stream>>>(x, rt, sxb, buf, bufb);
  gemm_sim<<<dim3(256), dim3(512), 0, stream>>>(sxb, bufb, part);
  reduce_max<<<dim3(BROWS / 2), dim3(64), 0, stream>>>(part, out);
}

// Round 7
// 172.477 us; speedup vs baseline: 2.2860x; 1.0436x over previous
//
#include <hip/hip_runtime.h>
#include <hip/hip_bf16.h>

// Problem: B=2048, DIM=2048, SKETCH=256, SIZE=131072
//   sx = normalize_rows(x @ R); out = 1 - max_row(sx @ buffer^T)

#define BROWS 2048
#define DIM   2048
#define SKDIM 256
#define NBUF  131072

// gemm_sim v8: A-in-registers. 512 blocks (16 m x 32 nc), 256 thr (4 waves,
// 2x2, wave tile 64x64), block tile 128 rows x 4096 cols. K=256 held fully
// in VGPRs (areg[4][8] = 128 VGPR). Window = BK=64 slice of one 128-col
// n-tile; only B streams through LDS: 4 slots x 16KB, stage g+3 at window g,
// counted vmcnt(8), ONE barrier per window. 2 blocks/CU -> cross-block
// overlap covers barrier/LDS stalls.
#define NGROUPS 32            // n-chunks (4096 cols each)
#define NT_PER  32            // 128-col n-tiles per block

typedef __attribute__((ext_vector_type(4))) float f32x4;
typedef __attribute__((ext_vector_type(8))) short bf16x8;
typedef __attribute__((ext_vector_type(4))) short bf16x4;

static __device__ inline unsigned short f2bf(float f) {
  unsigned u = __float_as_uint(f);
  unsigned r = u + 0x7FFFu + ((u >> 16) & 1u);  // round-to-nearest-even
  return (unsigned short)(r >> 16);
}

static __device__ inline bf16x8 cvt8(const float* __restrict__ p) {
  f32x4 a = *(const f32x4*)p;
  f32x4 b = *(const f32x4*)(p + 4);
  bf16x8 r;
  r[0] = (short)f2bf(a[0]); r[1] = (short)f2bf(a[1]);
  r[2] = (short)f2bf(a[2]); r[3] = (short)f2bf(a[3]);
  r[4] = (short)f2bf(b[0]); r[5] = (short)f2bf(b[1]);
  r[6] = (short)f2bf(b[2]); r[7] = (short)f2bf(b[3]);
  return r;
}

// K0: RT_bf[n][k] = bf16(R[k][n])   (256 x 2048)
__global__ void transpose_R(const float* __restrict__ R, unsigned short* __restrict__ rt) {
  int idx = blockIdx.x * 256 + threadIdx.x;
  int k = idx >> 8, n = idx & 255;
  rt[n * DIM + k] = f2bf(R[idx]);
}

// K1+K2 fused: blocks 0..31 = gemm_sketch; blocks 32..2079 = conv_buf.
__launch_bounds__(256)
__global__ void sketch_conv(const float* __restrict__ x, const unsigned short* __restrict__ rt,
                            unsigned short* __restrict__ sx,
                            const float* __restrict__ bufin, unsigned short* __restrict__ outb) {
  __shared__ unsigned short As[64][72];
  __shared__ unsigned short Bs[256][72];
  __shared__ float ssum[4][64];

  if (blockIdx.x >= 32) {
    // ---- conv path ----
    const int nvec = (NBUF * SKDIM) / 4;
    int stride = 2048 * 256;
    for (int i = (blockIdx.x - 32) * 256 + threadIdx.x; i < nvec; i += stride) {
      f32x4 v = ((const f32x4*)bufin)[i];
      bf16x4 r;
      r[0] = (short)f2bf(v[0]); r[1] = (short)f2bf(v[1]);
      r[2] = (short)f2bf(v[2]); r[3] = (short)f2bf(v[3]);
      ((bf16x4*)outb)[i] = r;
    }
    return;
  }

  // ---- sketch path (validated R0-R5) ----
  const int m0 = blockIdx.x * 64;
  const int tid = threadIdx.x;
  const int w = tid >> 6, l = tid & 63;
  const int lr = l & 15, q = l >> 4;

  f32x4 acc[4][4] = {};

  for (int k0 = 0; k0 < DIM; k0 += 64) {
    #pragma unroll
    for (int i = 0; i < 2; ++i) {
      int v = tid + i * 256;
      int r = v >> 3, vc = v & 7;
      *(bf16x8*)&As[r][vc * 8] = cvt8(x + (size_t)(m0 + r) * DIM + k0 + vc * 8);
    }
    #pragma unroll
    for (int i = 0; i < 8; ++i) {
      int v = tid + i * 256;
      int r = v >> 3, vc = v & 7;
      *(bf16x8*)&Bs[r][vc * 8] = *(const bf16x8*)(rt + (size_t)r * DIM + k0 + vc * 8);
    }
    __syncthreads();
    #pragma unroll
    for (int ks = 0; ks < 2; ++ks) {
      int kk = ks * 32 + q * 8;
      bf16x8 a[4], b[4];
      #pragma unroll
      for (int mi = 0; mi < 4; ++mi) a[mi] = *(bf16x8*)&As[mi * 16 + lr][kk];
      #pragma unroll
      for (int ni = 0; ni < 4; ++ni) b[ni] = *(bf16x8*)&Bs[w * 64 + ni * 16 + lr][kk];
      #pragma unroll
      for (int mi = 0; mi < 4; ++mi)
        #pragma unroll
        for (int ni = 0; ni < 4; ++ni)
          acc[mi][ni] = __builtin_amdgcn_mfma_f32_16x16x32_bf16(a[mi], b[ni], acc[mi][ni], 0, 0, 0);
    }
    __syncthreads();
  }

  float ps[4][4];
  #pragma unroll
  for (int mi = 0; mi < 4; ++mi)
    #pragma unroll
    for (int rg = 0; rg < 4; ++rg) {
      float s = acc[mi][0][rg] * acc[mi][0][rg] + acc[mi][1][rg] * acc[mi][1][rg]
              + acc[mi][2][rg] * acc[mi][2][rg] + acc[mi][3][rg] * acc[mi][3][rg];
      #pragma unroll
      for (int m = 1; m < 16; m <<= 1) s += __shfl_xor(s, m);
      ps[mi][rg] = s;
    }
  if (lr == 0) {
    #pragma unroll
    for (int mi = 0; mi < 4; ++mi)
      #pragma unroll
      for (int rg = 0; rg < 4; ++rg)
        ssum[w][mi * 16 + q * 4 + rg] = ps[mi][rg];
  }
  __syncthreads();

  #pragma unroll
  for (int mi = 0; mi < 4; ++mi)
    #pragma unroll
    for (int rg = 0; rg < 4; ++rg) {
      int r = mi * 16 + q * 4 + rg;
      float tot = ssum[0][r] + ssum[1][r] + ssum[2][r] + ssum[3][r];
      float inv = 1.0f / fmaxf(sqrtf(tot), 1e-12f);
      #pragma unroll
      for (int ni = 0; ni < 4; ++ni) {
        float val = acc[mi][ni][rg] * inv;
        sx[(size_t)(m0 + r) * SKDIM + w * 64 + ni * 16 + lr] = f2bf(val);
      }
    }
}

// K3 v8: A-in-regs sim row-max.
// LDS: 4 B-slots of [128 cols][64 k] bf16 (16KB each, row stride 128B,
// 8 16B col-slots, XOR key (row>>1)&7 applied to global SOURCE + ds_read).
// Window g = (nt, ks=g&3): slot = ks (compile-time via 4x unroll).
// Schedule: [vmcnt(counted); s_barrier; STAGE(g+3); 8 ds_read B; 32 MFMA
// (A from regs); fold at ks==3]. Stage lead ~3 windows; vmcnt(8) = 2 stages
// in flight. WAR: slot (g+3)&3 = (g-1)&3 readers drained before barrier(g).
__launch_bounds__(256, 2)
__global__ void gemm_sim(const unsigned short* __restrict__ sx,
                         const unsigned short* __restrict__ bufb,
                         float* __restrict__ partial) {
  __shared__ __align__(16) char lb[65536];

  // XCD-chunked swizzle (512 blocks = 8 XCDs x 64), m-fastest inner.
  const int gid = blockIdx.x;
  const int logical = (gid & 7) * 64 + (gid >> 3);
  const int mt = logical & 15;       // 0..15 m-tile (128 rows)
  const int nc = logical >> 4;       // 0..31 n-chunk (4096 cols)
  const int m0 = mt * 128;
  const int ncbase = nc * (NT_PER * 128);

  const int tid = threadIdx.x;
  const int w = tid >> 6, l = tid & 63;
  const int wr = w >> 1, wc = w & 1;        // wave grid 2 x 2
  const int lr = l & 15, q = l >> 4;

  // staging: LDS linear dest (row = j*32 + (tid>>3), 16B slot tid&7);
  // global source col-slot pre-swizzled by (row>>1)&7 = (tid>>4)&7.
  const int scol = ((tid & 7) ^ ((tid >> 4) & 7)) * 8;   // elements
  // read swizzle: chunk-c slot = (c*4+q) ^ ((lr>>1)&7)
  const int off0 = ((q ^ ((lr >> 1) & 7)) << 4);
  const int off1 = off0 ^ 64;

  // ---- A resident in registers: rows m0 + wr*64 + mi*16 + lr, k = kc*32+q*8
  bf16x8 areg[4][8];
  {
    const unsigned short* abase = sx + (size_t)(m0 + wr * 64 + lr) * SKDIM + q * 8;
    #pragma unroll
    for (int mi = 0; mi < 4; ++mi)
      #pragma unroll
      for (int kc = 0; kc < 8; ++kc)
        areg[mi][kc] = *(const bf16x8*)(abase + mi * 16 * SKDIM + kc * 32);
  }

  f32x4 acc[4][4] = {};
  float rm[4][4];
  #pragma unroll
  for (int mi = 0; mi < 4; ++mi)
    #pragma unroll
    for (int rg = 0; rg < 4; ++rg) rm[mi][rg] = -3.0e38f;

#define STAGE(nt_, ks_, slot_) do {                                            \
    const unsigned short* src_ = bufb                                          \
        + (size_t)(ncbase + (nt_) * 128 + (tid >> 3)) * SKDIM                  \
        + (ks_) * 64 + scol;                                                   \
    char* dst_ = lb + (slot_) * 16384 + tid * 16;                              \
    _Pragma("unroll")                                                          \
    for (int j_ = 0; j_ < 4; ++j_) {                                           \
      __builtin_amdgcn_global_load_lds(                                        \
          (const __attribute__((address_space(1))) unsigned int*)(src_ + j_ * 32 * SKDIM), \
          (__attribute__((address_space(3))) unsigned int*)(dst_ + j_ * 4096), \
          16, 0, 0);                                                           \
    }                                                                          \
  } while (0)

  // prologue: stage windows 0,1,2 (slots 0,1,2)
  STAGE(0, 0, 0);
  STAGE(0, 1, 1);
  STAGE(0, 2, 2);

  for (int nt = 0; nt < NT_PER; ++nt) {
    #pragma unroll
    for (int ks = 0; ks < 4; ++ks) {
      // counted vmcnt: 2 stages (8 loads) in flight, except tail
      if (ks == 2) {
        if (nt == NT_PER - 1) { asm volatile("s_waitcnt vmcnt(4)" ::: "memory"); }
        else                  { asm volatile("s_waitcnt vmcnt(8)" ::: "memory"); }
      } else if (ks == 3) {
        if (nt == NT_PER - 1) { asm volatile("s_waitcnt vmcnt(0)" ::: "memory"); }
        else                  { asm volatile("s_waitcnt vmcnt(8)" ::: "memory"); }
      } else {
        asm volatile("s_waitcnt vmcnt(8)" ::: "memory");
      }
      asm volatile("s_barrier" ::: "memory");

      // stage window g+3 into slot (ks+3)&3
      if (ks == 0) {
        if (nt <= NT_PER - 1) STAGE(nt, 3, 3);
      } else if (ks == 1) {
        if (nt < NT_PER - 1) STAGE(nt + 1, 0, 0);
      } else if (ks == 2) {
        if (nt < NT_PER - 1) STAGE(nt + 1, 1, 1);
      } else {
        if (nt < NT_PER - 1) STAGE(nt + 1, 2, 2);
      }

      // B frags from slot ks (8 ds_read_b128)
      const char* pb = lb + ks * 16384 + (wc * 64 + lr) * 128;
      bf16x8 bf0[4], bf1[4];
      #pragma unroll
      for (int ni = 0; ni < 4; ++ni) bf0[ni] = *(const bf16x8*)(pb + ni * 2048 + off0);
      #pragma unroll
      for (int ni = 0; ni < 4; ++ni) bf1[ni] = *(const bf16x8*)(pb + ni * 2048 + off1);

      __builtin_amdgcn_s_setprio(1);
      #pragma unroll
      for (int mi = 0; mi < 4; ++mi)
        #pragma unroll
        for (int ni = 0; ni < 4; ++ni)
          acc[mi][ni] = __builtin_amdgcn_mfma_f32_16x16x32_bf16(areg[mi][ks * 2], bf0[ni], acc[mi][ni], 0, 0, 0);
      #pragma unroll
      for (int mi = 0; mi < 4; ++mi)
        #pragma unroll
        for (int ni = 0; ni < 4; ++ni)
          acc[mi][ni] = __builtin_amdgcn_mfma_f32_16x16x32_bf16(areg[mi][ks * 2 + 1], bf1[ni], acc[mi][ni], 0, 0, 0);
      __builtin_amdgcn_s_setprio(0);

      if (ks == 3) {  // n-tile complete: fold row-max, reset acc
        #pragma unroll
        for (int mi = 0; mi < 4; ++mi)
          #pragma unroll
          for (int rg = 0; rg < 4; ++rg) {
            float v = fmaxf(fmaxf(acc[mi][0][rg], acc[mi][1][rg]),
                            fmaxf(acc[mi][2][rg], acc[mi][3][rg]));
            rm[mi][rg] = fmaxf(rm[mi][rg], v);
            #pragma unroll
            for (int ni = 0; ni < 4; ++ni) acc[mi][ni][rg] = 0.0f;
          }
      }
    }
  }
#undef STAGE

  // epilogue: reduce over the 16 cols held across lr lanes
  #pragma unroll
  for (int mi = 0; mi < 4; ++mi)
    #pragma unroll
    for (int rg = 0; rg < 4; ++rg) {
      float v = rm[mi][rg];
      v = fmaxf(v, __shfl_xor(v, 1));
      v = fmaxf(v, __shfl_xor(v, 2));
      v = fmaxf(v, __shfl_xor(v, 4));
      v = fmaxf(v, __shfl_xor(v, 8));
      rm[mi][rg] = v;
    }

  float* rmaxs = (float*)lb;   // reuse staging LDS: [2 wc][128 rows]
  __syncthreads();
  if (lr == 0) {
    #pragma unroll
    for (int mi = 0; mi < 4; ++mi)
      #pragma unroll
      for (int rg = 0; rg < 4; ++rg)
        rmaxs[wc * 128 + wr * 64 + mi * 16 + q * 4 + rg] = rm[mi][rg];
  }
  __syncthreads();
  if (tid < 128) {
    float v = fmaxf(rmaxs[tid], rmaxs[128 + tid]);
    partial[(size_t)(m0 + tid) * NGROUPS + nc] = v;
  }
}

// K4: out[r] = 1 - max over 32 partials. 2 rows per 64-thread block.
__global__ void reduce_max(const float* __restrict__ partial, float* __restrict__ out) {
  const int r = blockIdx.x * 2 + (threadIdx.x >> 5);
  const int c = threadIdx.x & 31;
  float m = partial[(size_t)r * NGROUPS + c];
  #pragma unroll
  for (int s = 1; s < 32; s <<= 1) m = fmaxf(m, __shfl_xor(m, s));
  if (c == 0) out[r] = 1.0f - m;
}

extern "C" void kernel_launch(void* const* d_in, const int* in_sizes, int n_in,
                              void* d_out, int out_size, void* d_ws, size_t ws_size,
                              hipStream_t stream) {
  const float* x   = (const float*)d_in[0];   // [2048, 2048]
  const float* R   = (const float*)d_in[1];   // [2048, 256]
  const float* buf = (const float*)d_in[2];   // [131072, 256]
  float* out = (float*)d_out;                  // [2048]

  char* ws = (char*)d_ws;
  // ws layout: rt 1MB | buf_bf 64MB | sx_bf 1MB | partial 256KB
  unsigned short* rt   = (unsigned short*)(ws);
  unsigned short* bufb = (unsigned short*)(ws + (1ull << 20));
  unsigned short* sxb  = (unsigned short*)(ws + (1ull << 20) + (64ull << 20));
  float*          part = (float*)         (ws + (1ull << 20) + (64ull << 20) + (1ull << 20));

  transpose_R<<<dim3((DIM * SKDIM) / 256), dim3(256), 0, stream>>>(R, rt);
  sketch_conv<<<dim3(2080), dim3(256), 0, stream>>>(x, rt, sxb, buf, bufb);
  gemm_sim<<<dim3(512), dim3(256), 0, stream>>>(sxb, bufb, part);
  reduce_max<<<dim3(BROWS / 2), dim3(64), 0, stream>>>(part, out);
}